// Round 2
// baseline (87331.140 us; speedup 1.0000x reference)
//
#include <hip/hip_runtime.h>

// Problem constants
#define B_   128
#define T_   128
#define E_   1024
#define H_   1024
#define A_   64
#define NH_  8
#define G_   3072
#define QK_  512
#define SCALE_ 0.125f

// ---------------------------------------------------------------------------
// JAX Threefry-2x32-20 (bit-exact) + XLA f32 erfinv path
// ---------------------------------------------------------------------------
__device__ __forceinline__ unsigned rotl32(unsigned x, int r) {
  return (x << r) | (x >> (32 - r));
}

__device__ __forceinline__ void tf2x32(unsigned k0, unsigned k1,
                                       unsigned x0, unsigned x1,
                                       unsigned& o0, unsigned& o1) {
  unsigned k2 = k0 ^ k1 ^ 0x1BD11BDAu;
  x0 += k0; x1 += k1;
  x0 += x1; x1 = rotl32(x1, 13); x1 ^= x0;
  x0 += x1; x1 = rotl32(x1, 15); x1 ^= x0;
  x0 += x1; x1 = rotl32(x1, 26); x1 ^= x0;
  x0 += x1; x1 = rotl32(x1,  6); x1 ^= x0;
  x0 += k1; x1 += k2 + 1u;
  x0 += x1; x1 = rotl32(x1, 17); x1 ^= x0;
  x0 += x1; x1 = rotl32(x1, 29); x1 ^= x0;
  x0 += x1; x1 = rotl32(x1, 16); x1 ^= x0;
  x0 += x1; x1 = rotl32(x1, 24); x1 ^= x0;
  x0 += k2; x1 += k0 + 2u;
  x0 += x1; x1 = rotl32(x1, 13); x1 ^= x0;
  x0 += x1; x1 = rotl32(x1, 15); x1 ^= x0;
  x0 += x1; x1 = rotl32(x1, 26); x1 ^= x0;
  x0 += x1; x1 = rotl32(x1,  6); x1 ^= x0;
  x0 += k0; x1 += k1 + 3u;
  x0 += x1; x1 = rotl32(x1, 17); x1 ^= x0;
  x0 += x1; x1 = rotl32(x1, 29); x1 ^= x0;
  x0 += x1; x1 = rotl32(x1, 16); x1 ^= x0;
  x0 += x1; x1 = rotl32(x1, 24); x1 ^= x0;
  x0 += k1; x1 += k2 + 4u;
  x0 += x1; x1 = rotl32(x1, 13); x1 ^= x0;
  x0 += x1; x1 = rotl32(x1, 15); x1 ^= x0;
  x0 += x1; x1 = rotl32(x1, 26); x1 ^= x0;
  x0 += x1; x1 = rotl32(x1,  6); x1 ^= x0;
  x0 += k2; x1 += k0 + 5u;
  o0 = x0; o1 = x1;
}

__device__ __forceinline__ float bits_to_normal(unsigned bits) {
  float uf = __uint_as_float((bits >> 9) | 0x3F800000u) - 1.0f;
  const float LO = -0.99999994f;
  float u = fmaxf(LO, uf * 2.0f + LO);
  float w = -log1pf(-u * u);
  float p;
  if (w < 5.0f) {
    w -= 2.5f;
    p = 2.81022636e-08f;
    p = fmaf(p, w, 3.43273939e-07f);
    p = fmaf(p, w, -3.5233877e-06f);
    p = fmaf(p, w, -4.39150654e-06f);
    p = fmaf(p, w, 0.00021858087f);
    p = fmaf(p, w, -0.00125372503f);
    p = fmaf(p, w, -0.00417768164f);
    p = fmaf(p, w, 0.246640727f);
    p = fmaf(p, w, 1.50140941f);
  } else {
    w = sqrtf(w) - 3.0f;
    p = -0.000200214257f;
    p = fmaf(p, w, 0.000100950558f);
    p = fmaf(p, w, 0.00134934322f);
    p = fmaf(p, w, -0.00367342844f);
    p = fmaf(p, w, 0.00573950773f);
    p = fmaf(p, w, -0.0076224613f);
    p = fmaf(p, w, 0.00943887047f);
    p = fmaf(p, w, 1.00167406f);
    p = fmaf(p, w, 2.83297682f);
  }
  return 1.41421356f * p * u;
}

__device__ __forceinline__ float sigmoidf_(float x) {
  return 1.0f / (1.0f + expf(-x));
}

__device__ __forceinline__ float ld_elem(const void* p, long i, int isb) {
  if (isb) {
    unsigned short u = ((const unsigned short*)p)[i];
    return __uint_as_float(((unsigned)u) << 16);
  }
  return ((const float*)p)[i];
}

// ---------------------------------------------------------------------------
// Software grid barrier (device-scope, cross-XCD safe).
// bar[0] = arrive counter, bar[1] = generation.
// Self-cleaning: arrive returns to 0 after each barrier; generation is
// compared by value so state survives graph replays.
// ---------------------------------------------------------------------------
#define NBLK_ 256

__device__ __forceinline__ void gsync(unsigned* bar, int tid) {
  __syncthreads();
  if (tid == 0) {
    __threadfence();  // release: flush this block's writes to device scope
    unsigned g = __hip_atomic_load(&bar[1], __ATOMIC_RELAXED,
                                   __HIP_MEMORY_SCOPE_AGENT);
    unsigned a = __hip_atomic_fetch_add(&bar[0], 1u, __ATOMIC_ACQ_REL,
                                        __HIP_MEMORY_SCOPE_AGENT);
    if (a == NBLK_ - 1u) {
      __hip_atomic_store(&bar[0], 0u, __ATOMIC_RELAXED,
                         __HIP_MEMORY_SCOPE_AGENT);
      __hip_atomic_store(&bar[1], g + 1u, __ATOMIC_RELEASE,
                         __HIP_MEMORY_SCOPE_AGENT);
    } else {
      while (__hip_atomic_load(&bar[1], __ATOMIC_RELAXED,
                               __HIP_MEMORY_SCOPE_AGENT) == g) {
        __builtin_amdgcn_s_sleep(1);
      }
      __threadfence();  // acquire: invalidate stale caches
    }
  }
  __syncthreads();
}

// ---------------------------------------------------------------------------
// dtype sniffer + converter (verified).  sniff also zeroes the grid barrier.
// ---------------------------------------------------------------------------
__global__ __launch_bounds__(256) void sniff_kernel(const void* encs, int* flag) {
  __shared__ int cnt;
  if (threadIdx.x == 0) cnt = 0;
  if (threadIdx.x < 2) ((unsigned*)flag)[8 + threadIdx.x] = 0u;  // grid barrier
  __syncthreads();
  const unsigned* w = (const unsigned*)encs;
  int c = 0;
  for (int i = threadIdx.x; i < 4096; i += 256) {
    unsigned e7 = (w[i] >> 8) & 0x7F;
    if (e7 >= 0x3B && e7 <= 0x41) c++;
  }
  atomicAdd(&cnt, c);
  __syncthreads();
  if (threadIdx.x == 0) flag[0] = (cnt > 2048) ? 1 : 0;
}

__global__ __launch_bounds__(256) void conv_kernel(const void* src, float* dst,
                                                   long n, const int* flag) {
  long i = (long)blockIdx.x * 256 + threadIdx.x;
  int isb = flag[0];
  if (i < n) dst[i] = ld_elem(src, i, isb);
}

// ---------------------------------------------------------------------------
// trans: build Wbig (2048x4096 interleaved-4), Wms (1024x2048), WkT (512x1024),
// Wenc4 (1024x4096), bias4, zero xh/h, skeys.  grid (16384, 5)
// ---------------------------------------------------------------------------
__global__ __launch_bounds__(256) void trans_kernel(
    const void* W_ih, const void* W_hh, const void* W_mu, const void* W_sig,
    const void* W_k, const float* __restrict__ bihF, const float* __restrict__ bhhF,
    float* __restrict__ Wbig, float* __restrict__ Wms, float* __restrict__ WkT,
    float* __restrict__ Wenc4, float* __restrict__ bias4,
    float* __restrict__ xh, float* __restrict__ h, unsigned* __restrict__ skeys,
    const int* flag)
{
  long idx = (long)blockIdx.x * 256 + threadIdx.x;
  int y = blockIdx.y;
  int isb = flag[0];
  if (y == 0) {
    if (idx < 4194304) {
      int e = (int)(idx & 1023); int col = (int)(idx >> 10);
      int j = col >> 2, c = col & 3;
      float v = 0.f;
      if (c < 3) v = ld_elem(W_ih, (long)(c * 1024 + j) * 2048 + 1024 + e, isb);
      Wbig[(long)e * 4096 + col] = v;
    }
  } else if (y == 1) {
    if (idx < 4194304) {
      int e = (int)(idx & 1023); int col = (int)(idx >> 10);
      int j = col >> 2, c = col & 3;
      float v = 0.f;
      if (c == 0)      v = ld_elem(W_hh, (long)j * 1024 + e, isb);
      else if (c == 1) v = ld_elem(W_hh, (long)(1024 + j) * 1024 + e, isb);
      else if (c == 3) v = ld_elem(W_hh, (long)(2048 + j) * 1024 + e, isb);
      Wbig[(long)(1024 + e) * 4096 + col] = v;
    }
  } else if (y == 2) {
    if (idx < 2097152) {
      int k = (int)(idx >> 11), n = (int)(idx & 2047);
      float v = (n < 1024) ? ld_elem(W_mu, (long)k * 1024 + n, isb)
                           : ld_elem(W_sig, (long)k * 1024 + (n - 1024), isb);
      Wms[idx] = v;
    }
  } else if (y == 3) {
    if (idx < 524288) {
      int qk = (int)(idx >> 10), e = (int)(idx & 1023);
      WkT[idx] = ld_elem(W_k, (long)e * 512 + qk, isb);
    }
    if (idx < 4096) {
      int j = (int)(idx >> 2), c = (int)(idx & 3);
      float v;
      if (c == 0)      v = bihF[j] + bhhF[j];
      else if (c == 1) v = bihF[1024 + j] + bhhF[1024 + j];
      else if (c == 2) v = bihF[2048 + j];
      else             v = bhhF[2048 + j];
      bias4[idx] = v;
    }
    if (idx < 262144) xh[idx] = 0.f;
    if (idx < 131072) h[idx] = 0.f;
    if (idx < 128) {
      unsigned o0, o1;
      tf2x32(0u, 1234u, 0u, (unsigned)idx, o0, o1);
      skeys[2 * idx] = o0; skeys[2 * idx + 1] = o1;
    }
  } else {
    if (idx < 4194304) {
      int e = (int)(idx & 1023); int col = (int)(idx >> 10);
      int j = col >> 2, c = col & 3;
      float v = 0.f;
      if (c < 3) v = ld_elem(W_ih, (long)(c * 1024 + j) * 2048 + e, isb);
      Wenc4[(long)e * 4096 + col] = v;
    }
  }
}

// ---------------------------------------------------------------------------
// consts: bqk[h][e], qbc[h], bvo[e].  grid (32)
// ---------------------------------------------------------------------------
__global__ __launch_bounds__(256) void consts_kernel(
    const float* __restrict__ bqF, const float* __restrict__ bkF,
    const float* __restrict__ bvF, const float* __restrict__ boF,
    const float* __restrict__ WkT, const float* __restrict__ WoF,
    float* __restrict__ bqk, float* __restrict__ qbc, float* __restrict__ bvo)
{
  int idx = blockIdx.x * 256 + threadIdx.x;
  int hh = idx >> 10, e = idx & 1023;
  float s = 0.f;
  for (int a = 0; a < 64; ++a)
    s += bqF[hh * 64 + a] * WkT[(long)(hh * 64 + a) * 1024 + e];
  bqk[idx] = s;
  if (idx < 1024) {
    float v = boF[idx];
    for (int ha = 0; ha < 512; ++ha) v += bvF[ha] * WoF[(long)ha * 1024 + idx];
    bvo[idx] = v;
  }
  if (idx < 8) {
    float v = 0.f;
    for (int a = 0; a < 64; ++a) v += bqF[idx * 64 + a] * bkF[idx * 64 + a];
    qbc[idx] = v;
  }
}

// ---------------------------------------------------------------------------
// Mega-kernel argument block
// ---------------------------------------------------------------------------
struct MegaArgs {
  const float *WbigF, *WmsF, *WkTF, *WqF, *WvF, *WoF;
  const float *bmuF, *bsigF, *bkF, *bias4, *bqk, *qbc, *bvo;
  const unsigned *skeys;
  const float *gie4;
  float *xh, *hbuf, *gsumP, *musigP, *qP, *tmat, *qbv, *scg;
  float *ctxE, *ctxhP, *ctxvP, *mus, *sigs, *s;
  unsigned *bar;
};

// ---------------------------------------------------------------------------
// mm128 device: 128x128 tile, 8x8/thread, split-K partial store.
// ---------------------------------------------------------------------------
__device__ void mm128_dev(float* smem,
    const float* A, long lda, long zA, int nsumA, long psA,
    const float* Bm, long ldb, long zB,
    float* C, long ldc, long zC, long pstride,
    int Ktot, int S, int bx, int by, int zz, int tid)
{
  int head = zz / S, sp = zz - head * S;
  int Kc = Ktot / S;
  long kb = (long)sp * Kc;
  A += (long)head * zA;
  Bm += (long)head * zB;
  C += (long)head * zC + (long)sp * pstride;
  long m0 = (long)by * 128;
  long n0 = (long)bx * 128;
  float* As = smem;            // [16][132]
  float* Bs = smem + 2112;     // [16][132]
  int tx = tid & 15, ty = tid >> 4;
  int am = tid >> 2, ac = tid & 3;
  int bk = tid >> 5, bn = tid & 31;
  float acc[8][8];
  #pragma unroll
  for (int i = 0; i < 8; ++i)
    #pragma unroll
    for (int j = 0; j < 8; ++j) acc[i][j] = 0.f;

  for (int k0 = 0; k0 < Kc; k0 += 16) {
    const float* Ap0 = A + (m0 + am) * lda + kb + k0 + 4 * ac;
    const float* Ap1 = A + (m0 + am + 64) * lda + kb + k0 + 4 * ac;
    float4 a0 = *(const float4*)Ap0;
    float4 a1 = *(const float4*)Ap1;
    for (int s2 = 1; s2 < nsumA; ++s2) {
      float4 t0 = *(const float4*)(Ap0 + (long)s2 * psA);
      float4 t1 = *(const float4*)(Ap1 + (long)s2 * psA);
      a0.x += t0.x; a0.y += t0.y; a0.z += t0.z; a0.w += t0.w;
      a1.x += t1.x; a1.y += t1.y; a1.z += t1.z; a1.w += t1.w;
    }
    float4 b0 = *(const float4*)(Bm + (kb + k0 + bk) * ldb + n0 + 4 * bn);
    float4 b1 = *(const float4*)(Bm + (kb + k0 + bk + 8) * ldb + n0 + 4 * bn);
    __syncthreads();
    As[(4 * ac + 0) * 132 + am] = a0.x; As[(4 * ac + 1) * 132 + am] = a0.y;
    As[(4 * ac + 2) * 132 + am] = a0.z; As[(4 * ac + 3) * 132 + am] = a0.w;
    As[(4 * ac + 0) * 132 + am + 64] = a1.x; As[(4 * ac + 1) * 132 + am + 64] = a1.y;
    As[(4 * ac + 2) * 132 + am + 64] = a1.z; As[(4 * ac + 3) * 132 + am + 64] = a1.w;
    *(float4*)&Bs[bk * 132 + 4 * bn] = b0;
    *(float4*)&Bs[(bk + 8) * 132 + 4 * bn] = b1;
    __syncthreads();
    #pragma unroll
    for (int kk = 0; kk < 16; ++kk) {
      float4 av0 = *(const float4*)&As[kk * 132 + ty * 4];
      float4 av1 = *(const float4*)&As[kk * 132 + 64 + ty * 4];
      float4 bv0 = *(const float4*)&Bs[kk * 132 + tx * 4];
      float4 bv1 = *(const float4*)&Bs[kk * 132 + 64 + tx * 4];
      float amv[8] = {av0.x, av0.y, av0.z, av0.w, av1.x, av1.y, av1.z, av1.w};
      float bnv[8] = {bv0.x, bv0.y, bv0.z, bv0.w, bv1.x, bv1.y, bv1.z, bv1.w};
      #pragma unroll
      for (int i = 0; i < 8; ++i)
        #pragma unroll
        for (int j = 0; j < 8; ++j)
          acc[i][j] = fmaf(amv[i], bnv[j], acc[i][j]);
    }
  }

  #pragma unroll
  for (int i = 0; i < 8; ++i) {
    long r = m0 + (long)(i >> 2) * 64 + ty * 4 + (i & 3);
    float4 v0 = {acc[i][0], acc[i][1], acc[i][2], acc[i][3]};
    float4 v1 = {acc[i][4], acc[i][5], acc[i][6], acc[i][7]};
    *(float4*)(C + r * ldc + n0 + tx * 4) = v0;
    *(float4*)(C + r * ldc + n0 + 64 + tx * 4) = v1;
  }
}

// ---------------------------------------------------------------------------
// mm64s device: 64x64 tile, 4x4/thread, split-K partial store, A can sum nsumA
// ---------------------------------------------------------------------------
__device__ void mm64s_dev(float* smem,
    const float* A, long lda, long zA, int nsumA, long psA,
    const float* Bm, long ldb, long zB,
    float* C, long ldc, long zC, long pstride,
    int Ktot, int S, int bx, int by, int zz, int tid)
{
  int head = zz / S, sp = zz - head * S;
  int Kc = Ktot / S;
  long kb = (long)sp * Kc;
  A += (long)head * zA; Bm += (long)head * zB;
  C += (long)head * zC + (long)sp * pstride;
  long n0 = (long)bx * 64;
  long m0 = (long)by * 64;
  float* As = smem;            // [16][68]
  float* Bs = smem + 1088;     // [16][68]
  int tx = tid & 15, ty = tid >> 4;
  int ar = tid >> 2, ac = tid & 3;
  int br = tid >> 4, bc = tid & 15;
  float acc[4][4];
  #pragma unroll
  for (int i = 0; i < 4; ++i)
    #pragma unroll
    for (int j = 0; j < 4; ++j) acc[i][j] = 0.f;

  for (int k0 = 0; k0 < Kc; k0 += 16) {
    const float* Ap = A + (m0 + ar) * lda + kb + k0 + 4 * ac;
    float4 a4 = *(const float4*)Ap;
    for (int s2 = 1; s2 < nsumA; ++s2) {
      float4 t = *(const float4*)(Ap + (long)s2 * psA);
      a4.x += t.x; a4.y += t.y; a4.z += t.z; a4.w += t.w;
    }
    float4 b4 = *(const float4*)(Bm + (kb + k0 + br) * ldb + n0 + 4 * bc);
    __syncthreads();
    As[(4 * ac + 0) * 68 + ar] = a4.x; As[(4 * ac + 1) * 68 + ar] = a4.y;
    As[(4 * ac + 2) * 68 + ar] = a4.z; As[(4 * ac + 3) * 68 + ar] = a4.w;
    *(float4*)(&Bs[br * 68 + 4 * bc]) = b4;
    __syncthreads();
    #pragma unroll
    for (int kk = 0; kk < 16; ++kk) {
      float4 av = *(const float4*)(&As[kk * 68 + 4 * ty]);
      float4 bv = *(const float4*)(&Bs[kk * 68 + 4 * tx]);
      float amv[4] = {av.x, av.y, av.z, av.w};
      float bnv[4] = {bv.x, bv.y, bv.z, bv.w};
      #pragma unroll
      for (int im = 0; im < 4; ++im)
        #pragma unroll
        for (int jn = 0; jn < 4; ++jn)
          acc[im][jn] = fmaf(amv[im], bnv[jn], acc[im][jn]);
    }
  }
  #pragma unroll
  for (int im = 0; im < 4; ++im) {
    long m = m0 + ty * 4 + im;
    float4 v = {acc[im][0], acc[im][1], acc[im][2], acc[im][3]};
    *(float4*)(C + m * ldc + n0 + tx * 4) = v;
  }
}

// ---------------------------------------------------------------------------
// GRU epilogue (port of gru_epi, per virtual index)
// ---------------------------------------------------------------------------
__device__ void gru_dev(int idx, const MegaArgs& a) {
  int b = idx >> 10, j = idx & 1023;
  float4 v = ((const float4*)a.gie4)[(long)b * 1024 + j];
  float4 bb4 = ((const float4*)a.bias4)[j];
  v.x += bb4.x; v.y += bb4.y; v.z += bb4.z; v.w += bb4.w;
  #pragma unroll
  for (int s2 = 0; s2 < 8; ++s2) {
    float4 t = ((const float4*)a.gsumP)[(long)s2 * 131072 + (long)b * 1024 + j];
    v.x += t.x; v.y += t.y; v.z += t.z; v.w += t.w;
  }
  float r = sigmoidf_(v.x);
  float z = sigmoidf_(v.y);
  float n = tanhf(v.z + r * v.w);
  float ho = a.hbuf[idx];
  float hn = (1.0f - z) * n + z * ho;
  a.hbuf[idx] = hn;
  a.xh[(long)b * 2048 + 1024 + j] = hn;
}

// ---------------------------------------------------------------------------
// Fused mu/sig epilogue + gen of s row `step` (2 elements per thread)
// ---------------------------------------------------------------------------
__device__ void musig_gen_dev(int bid, int tid, int step, const MegaArgs& a) {
  unsigned sk0 = a.skeys[2 * step], sk1 = a.skeys[2 * step + 1];
  #pragma unroll
  for (int k = 0; k < 2; ++k) {
    int el = bid * 256 + tid + k * 65536;
    int b = el >> 10, e = el & 1023;
    float mu = a.bmuF[e], xg = a.bsigF[e];
    #pragma unroll
    for (int s2 = 0; s2 < 8; ++s2) {
      mu += a.musigP[(long)s2 * 262144 + (long)b * 2048 + e];
      xg += a.musigP[(long)s2 * 262144 + (long)b * 2048 + 1024 + e];
    }
    float sig = fmaxf(xg, 0.0f) + log1pf(expf(-fabsf(xg)));
    a.mus[((long)b * T_ + step) * E_ + e] = mu;
    a.sigs[((long)b * T_ + step) * E_ + e] = sig;
    unsigned f = (unsigned)(b * (T_ * E_) + step * E_ + e);
    unsigned o0, o1;
    tf2x32(sk0, sk1, 0u, f, o0, o1);
    a.s[((long)b * T_ + step) * E_ + e] = fmaf(bits_to_normal(o0 ^ o1), sig, mu);
  }
}

// ---------------------------------------------------------------------------
// gen_s rows [lo, hi) with step-`step` keys, distributed across nb blocks
// ---------------------------------------------------------------------------
__device__ void gen_rows_dev(int lo, int hi, int lbid, int nb, int step,
                             const MegaArgs& a, int tid) {
  int nvb = (hi - lo) * 128;
  if (nvb <= 0) return;
  unsigned sk0 = a.skeys[2 * step], sk1 = a.skeys[2 * step + 1];
  for (int vb = lbid; vb < nvb; vb += nb) {
    int t = lo + (vb >> 7);
    int b = vb & 127;
    int e = tid * 4;
    unsigned f = (unsigned)(b * (T_ * E_) + t * E_ + e);
    unsigned o0, o1;
    float nv[4];
    tf2x32(sk0, sk1, 0u, f + 0u, o0, o1); nv[0] = bits_to_normal(o0 ^ o1);
    tf2x32(sk0, sk1, 0u, f + 1u, o0, o1); nv[1] = bits_to_normal(o0 ^ o1);
    tf2x32(sk0, sk1, 0u, f + 2u, o0, o1); nv[2] = bits_to_normal(o0 ^ o1);
    tf2x32(sk0, sk1, 0u, f + 3u, o0, o1); nv[3] = bits_to_normal(o0 ^ o1);
    long i4 = (((long)b * T_ + t) * E_ + e) >> 2;
    float4 mu = ((const float4*)a.mus)[i4];
    float4 sg = ((const float4*)a.sigs)[i4];
    float4 out;
    out.x = fmaf(nv[0], sg.x, mu.x);
    out.y = fmaf(nv[1], sg.y, mu.y);
    out.z = fmaf(nv[2], sg.z, mu.z);
    out.w = fmaf(nv[3], sg.w, mu.w);
    ((float4*)a.s)[i4] = out;
  }
}

// ---------------------------------------------------------------------------
// t-matrix (port of t_kernel)
// ---------------------------------------------------------------------------
__device__ void tk_dev(float* smem, int vb, const MegaArgs& a, int tid) {
  int bx = vb & 3, hh = (vb >> 2) & 7, bz = vb >> 5;
  int e = bx * 256 + tid;
  int b0 = bz * 8;
  float* q_l = smem;  // [8][64]
  __syncthreads();
  for (int idx2 = tid; idx2 < 512; idx2 += 256) {
    int bb = idx2 >> 6, aa = idx2 & 63;
    float v = 0.f;
    #pragma unroll
    for (int s2 = 0; s2 < 8; ++s2)
      v += a.qP[(long)s2 * 65536 + (long)(b0 + bb) * 512 + hh * 64 + aa];
    q_l[bb * 64 + aa] = v;
  }
  __syncthreads();
  float acc[8];
  #pragma unroll
  for (int bb = 0; bb < 8; ++bb) acc[bb] = 0.f;
  for (int aa = 0; aa < 64; ++aa) {
    float wv = a.WkTF[(long)(hh * 64 + aa) * 1024 + e];
    #pragma unroll
    for (int bb = 0; bb < 8; ++bb) acc[bb] = fmaf(q_l[bb * 64 + aa], wv, acc[bb]);
  }
  float bq_ = a.bqk[hh * 1024 + e];
  #pragma unroll
  for (int bb = 0; bb < 8; ++bb)
    a.tmat[((long)(b0 + bb) * NH_ + hh) * 1024 + e] = acc[bb] + bq_;
  if (bx == 0 && tid < 8) {
    int bb = tid;
    float sm2 = a.qbc[hh];
    for (int aa = 0; aa < 64; ++aa) sm2 += q_l[bb * 64 + aa] * a.bkF[hh * 64 + aa];
    a.qbv[(b0 + bb) * NH_ + hh] = sm2;
  }
}

// ---------------------------------------------------------------------------
// scores (port of scores_kernel)
// ---------------------------------------------------------------------------
__device__ void sc_dev(float* smem, int jt, int b, int step, const MegaArgs& a,
                       int tid) {
  int jbase = jt * 32;
  float* s_ch = smem;            // [32][132]
  float* t_ch = smem + 32 * 132; // [8][132]
  int hh = tid >> 5, jj = tid & 31;
  int j = jbase + jj;
  float acc = 0.f;
  for (int e0 = 0; e0 < 1024; e0 += 128) {
    __syncthreads();
    #pragma unroll
    for (int q = 0; q < 4; ++q) {
      int f = tid + q * 256;
      int jr = f >> 5, e4 = f & 31;
      int jg = jbase + jr;
      if (jg <= step)
        *(float4*)&s_ch[jr * 132 + e4 * 4] =
            *(const float4*)&a.s[((long)b * T_ + jg) * E_ + e0 + e4 * 4];
    }
    {
      int e4 = tid & 31, h2 = tid >> 5;
      *(float4*)&t_ch[h2 * 132 + e4 * 4] =
          *(const float4*)&a.tmat[((long)b * NH_ + h2) * E_ + e0 + e4 * 4];
    }
    __syncthreads();
    if (j <= step) {
      #pragma unroll
      for (int e4 = 0; e4 < 32; ++e4) {
        float4 sv = *(const float4*)&s_ch[jj * 132 + e4 * 4];
        float4 tv = *(const float4*)&t_ch[hh * 132 + e4 * 4];
        acc = fmaf(sv.x, tv.x, acc);
        acc = fmaf(sv.y, tv.y, acc);
        acc = fmaf(sv.z, tv.z, acc);
        acc = fmaf(sv.w, tv.w, acc);
      }
    }
  }
  if (j <= step)
    a.scg[((long)b * NH_ + hh) * T_ + j] = (acc + a.qbv[b * NH_ + hh]) * SCALE_;
}

// ---------------------------------------------------------------------------
// softmax + ctx (port of ctx_kernel)
// ---------------------------------------------------------------------------
__device__ void ctx_dev(float* smem, int et, int b, int step, const MegaArgs& a,
                        int tid) {
  float* w_l = smem;         // [8][128]
  float* s_l = smem + 1024;  // [32][68]
  __syncthreads();
  {
    int hh = tid >> 5, l = tid & 31;
    const float* sc = a.scg + ((long)b * NH_ + hh) * T_;
    float m = -3.0e38f;
    for (int j = l; j <= step; j += 32) m = fmaxf(m, sc[j]);
    for (int off = 16; off; off >>= 1) m = fmaxf(m, __shfl_xor(m, off, 32));
    float d = 0.f;
    for (int j = l; j <= step; j += 32) {
      float pe = expf(sc[j] - m);
      w_l[hh * T_ + j] = pe;
      d += pe;
    }
    for (int off = 16; off; off >>= 1) d += __shfl_xor(d, off, 32);
    float inv = 1.0f / d;
    for (int j = l; j <= step; j += 32) w_l[hh * T_ + j] *= inv;
  }
  int e = tid & 63, hp = tid >> 6;
  float acc0 = 0.f, acc1 = 0.f;
  for (int jc = 0; jc <= step; jc += 32) {
    __syncthreads();
    #pragma unroll
    for (int q = 0; q < 8; ++q) {
      int f = tid + q * 256;
      int jr = f >> 6, ee = f & 63;
      int jg = jc + jr;
      if (jg <= step)
        s_l[jr * 68 + ee] = a.s[((long)b * T_ + jg) * E_ + et * 64 + ee];
    }
    __syncthreads();
    int jmax = min(31, step - jc);
    for (int jr = 0; jr <= jmax; ++jr) {
      float sv = s_l[jr * 68 + e];
      acc0 = fmaf(w_l[hp * T_ + jc + jr], sv, acc0);
      acc1 = fmaf(w_l[(hp + 4) * T_ + jc + jr], sv, acc1);
    }
  }
  a.ctxE[((long)b * NH_ + hp) * E_ + et * 64 + e] = acc0;
  a.ctxE[((long)b * NH_ + hp + 4) * E_ + et * 64 + e] = acc1;
}

// ---------------------------------------------------------------------------
// finalize xh ctx half (sums 8 O partials)
// ---------------------------------------------------------------------------
__device__ void fin_dev(int vb, int tid, const MegaArgs& a) {
  int i4 = vb * 256 + tid;  // < 32768 float4s
  int b = i4 >> 8, e4 = i4 & 255;
  float4 v = ((const float4*)a.bvo)[e4];
  #pragma unroll
  for (int s2 = 0; s2 < 8; ++s2) {
    float4 t = ((const float4*)a.ctxvP)[(long)s2 * 32768 + (long)b * 256 + e4];
    v.x += t.x; v.y += t.y; v.z += t.z; v.w += t.w;
  }
  ((float4*)a.xh)[(long)b * 512 + e4] = v;
}

// ---------------------------------------------------------------------------
// Prep-only standalone mm128 wrapper (for gie4 = encs @ Wenc4)
// ---------------------------------------------------------------------------
__global__ __launch_bounds__(256) void mm128_k(
    const float* A, long lda, long zA, int nsumA, long psA,
    const float* Bm, long ldb, long zB,
    float* C, long ldc, long zC, long pstride, int Ktot, int S)
{
  __shared__ __align__(16) float smem[4224];
  mm128_dev(smem, A, lda, zA, nsumA, psA, Bm, ldb, zB, C, ldc, zC, pstride,
            Ktot, S, blockIdx.x, blockIdx.y, blockIdx.z, threadIdx.x);
}

// ---------------------------------------------------------------------------
// THE mega-kernel: whole 128-step scan, plain launch (graph-capture safe),
// 256 blocks x 256 threads (1 block/CU guaranteed co-resident),
// software grid barrier, 11 syncs per step.
// gen_s of rows < i is independent work, overlapped into the G1/G2/Q phases.
// ---------------------------------------------------------------------------
__global__ __launch_bounds__(256) void megakernel(MegaArgs a) {
  const int bid = blockIdx.x;
  const int tid = threadIdx.x;
  unsigned* bar = a.bar;
  __shared__ __align__(16) float smem[5280];

  #pragma unroll 1
  for (int i = 0; i < T_; ++i) {
    int r1 = (i * 7) / 12;   // gen rows [0,r1) in P1
    int r2 = (i * 10) / 12;  // gen rows [r1,r2) in P3, [r2,i) in P5
    // P1: G1 partials (256 subs: 32 n-tiles x 8 k-splits) + gen_s [0,r1)
    mm128_dev(smem, a.xh, 2048, 0, 1, 0, a.WbigF, 4096, 0,
              a.gsumP, 4096, 0, 524288, 2048, 8, bid & 31, 0, bid >> 5, tid);
    gen_rows_dev(0, r1, bid, 256, i, a, tid);
    gsync(bar, tid);
    // P2: GRU epilogue (512 vblocks)
    gru_dev(bid * 256 + tid, a);
    gru_dev((bid + 256) * 256 + tid, a);
    gsync(bar, tid);
    // P3: G2 partials (128 subs) on blocks <128; gen_s [r1,r2) on the rest
    if (bid < 128)
      mm128_dev(smem, a.hbuf, 1024, 0, 1, 0, a.WmsF, 2048, 0,
                a.musigP, 2048, 0, 262144, 1024, 8, bid & 15, 0, bid >> 4, tid);
    else
      gen_rows_dev(r1, r2, bid - 128, 128, i, a, tid);
    gsync(bar, tid);
    // P4: fused mu/sig epilogue + gen of s row i (all blocks)
    musig_gen_dev(bid, tid, i, a);
    gsync(bar, tid);
    // P5: Q partials (128 subs: 8n x 2m x 8k) on blocks <128; gen_s [r2,i)
    if (bid < 128)
      mm64s_dev(smem, a.s + (long)i * E_, (long)T_ * E_, 0, 1, 0,
                a.WqF, 512, 0, a.qP, 512, 0, 65536, 1024, 8,
                bid & 7, (bid >> 3) & 1, bid >> 4, tid);
    else
      gen_rows_dev(r2, i, bid - 128, 128, i, a, tid);
    gsync(bar, tid);
    // P6: t-matrix (512 vblocks)
    for (int vb = bid; vb < 512; vb += 256) tk_dev(smem, vb, a, tid);
    gsync(bar, tid);
    // P7: scores
    {
      int nvb = ((i + 32) / 32) * 128;
      for (int vb = bid; vb < nvb; vb += 256)
        sc_dev(smem, vb >> 7, vb & 127, i, a, tid);
    }
    gsync(bar, tid);
    // P8: softmax + ctx (2048 vblocks)
    for (int vb = bid; vb < 2048; vb += 256)
      ctx_dev(smem, vb & 15, vb >> 4, i, a, tid);
    gsync(bar, tid);
    // P9: V partials (64 subs, per-head K=1024 split-4)
    if (bid < 64)
      mm64s_dev(smem, a.ctxE, 8192, 1024, 1, 0, a.WvF, 512, 64,
                a.ctxhP, 512, 64, 65536, 1024, 4, 0, bid & 1, bid >> 1, tid);
    gsync(bar, tid);
    // P10: O partials (256 subs: 16n x 2m x 8k, sums 4 V partials)
    mm64s_dev(smem, a.ctxhP, 512, 0, 4, 65536, a.WoF, 1024, 0,
              a.ctxvP, 1024, 0, 131072, 512, 8,
              bid & 15, (bid >> 4) & 1, bid >> 5, tid);
    gsync(bar, tid);
    // P11: finalize xh ctx half
    if (bid < 128) fin_dev(bid, tid, a);
    gsync(bar, tid);
  }
}

// ---------------------------------------------------------------------------
// Host side
// ---------------------------------------------------------------------------
extern "C" void kernel_launch(void* const* d_in, const int* in_sizes, int n_in,
                              void* d_out, int out_size, void* d_ws, size_t ws_size,
                              hipStream_t stream) {
  (void)in_sizes; (void)n_in; (void)out_size; (void)ws_size;
  const void* encs  = d_in[0];
  const void* W_ih  = d_in[1];
  const void* W_hh  = d_in[2];
  const void* b_ih  = d_in[3];
  const void* b_hh  = d_in[4];
  const void* W_mu  = d_in[5];
  const void* b_mu  = d_in[6];
  const void* W_sig = d_in[7];
  const void* b_sig = d_in[8];
  const void* W_q   = d_in[9];
  const void* b_q   = d_in[10];
  const void* W_k   = d_in[11];
  const void* b_k   = d_in[12];
  const void* W_v   = d_in[13];
  const void* b_v   = d_in[14];
  const void* W_o   = d_in[15];
  const void* b_o   = d_in[16];

  float* s = (float*)d_out;
  float* w = (float*)d_ws;

  int*   flag   = (int*)w;
  unsigned* bar = ((unsigned*)w) + 8;   // bar[0]=arrive, bar[1]=gen (in flag page)
  float* p      = w + 1024;
  float* WbigF  = p;  p += (size_t)2048 * 4096;
  float* WmsF   = p;  p += (size_t)1024 * 2048;
  float* WkTF   = p;  p += (size_t)512 * 1024;
  float* WqF    = p;  p += (size_t)1024 * 512;
  float* WvF    = p;  p += (size_t)1024 * 512;
  float* WoF    = p;  p += (size_t)512 * 1024;
  float* encsF  = p;  p += (size_t)B_ * E_;
  float* bihF   = p;  p += 4096;
  float* bhhF   = p;  p += 4096;
  float* bmuF   = p;  p += 1024;
  float* bsigF  = p;  p += 1024;
  float* bqF    = p;  p += 1024;
  float* bkF    = p;  p += 1024;
  float* bvF    = p;  p += 1024;
  float* boF    = p;  p += 1024;
  float* bias4  = p;  p += 4096;
  float* bqk    = p;  p += 8192;
  float* qbc    = p;  p += 1024;
  float* bvo    = p;  p += 1024;
  unsigned* skeys = (unsigned*)p; p += 1024;
  float* gie4   = p;  p += (size_t)B_ * 4096;
  float* xh     = p;  p += (size_t)B_ * 2048;     // [ctx | h]
  float* hbuf   = p;  p += (size_t)B_ * 1024;
  float* gsumP  = p;  p += (size_t)8 * B_ * 4096; // aliased: Wenc4 (prep), ctxvP (P10/P11)
  float* musigP = p;  p += (size_t)8 * B_ * 2048;
  float* qP     = p;  p += (size_t)8 * B_ * 512;
  float* tmat   = p;  p += (size_t)B_ * NH_ * E_;
  float* qbv    = p;  p += 1024;
  float* scg    = p;  p += (size_t)B_ * NH_ * T_;
  float* ctxE   = p;  p += (size_t)B_ * NH_ * E_;
  float* ctxhP  = p;  p += (size_t)4 * B_ * 512;
  float* mus    = p;  p += (size_t)B_ * T_ * E_;
  float* sigs   = p;  p += (size_t)B_ * T_ * E_;
  float* Wenc4  = gsumP;  // prep-only alias (consumed before first G1 write)
  float* ctxvP  = gsumP;  // in-loop alias: gsumP is dead between P2 and next P1

  // ---- prep ----
  sniff_kernel<<<1, 256, 0, stream>>>(encs, flag);
  auto conv = [&](const void* src, float* dst, long n) {
    conv_kernel<<<dim3((unsigned)((n + 255) / 256)), 256, 0, stream>>>(src, dst, n, flag);
  };
  conv(encs,  encsF, (long)B_ * E_);
  conv(b_ih,  bihF,  G_);
  conv(b_hh,  bhhF,  G_);
  conv(b_mu,  bmuF,  1024);
  conv(b_sig, bsigF, 1024);
  conv(b_q,   bqF,   512);
  conv(b_k,   bkF,   512);
  conv(b_v,   bvF,   512);
  conv(b_o,   boF,   1024);
  conv(W_q,   WqF,   (long)1024 * 512);
  conv(W_v,   WvF,   (long)1024 * 512);
  conv(W_o,   WoF,   (long)512 * 1024);

  trans_kernel<<<dim3(16384, 5), 256, 0, stream>>>(
      W_ih, W_hh, W_mu, W_sig, W_k, bihF, bhhF,
      WbigF, WmsF, WkTF, Wenc4, bias4, xh, hbuf, skeys, flag);
  consts_kernel<<<dim3(32), 256, 0, stream>>>(
      bqF, bkF, bvF, boF, WkTF, WoF, bqk, qbc, bvo);
  // gie4 = encs @ Wenc4  (reads the gsumP-aliased Wenc4 BEFORE the loop)
  mm128_k<<<dim3(32, 1, 1), 256, 0, stream>>>(
      encsF, 1024, 0, 1, 0, Wenc4, 4096, 0, gie4, 4096, 0, 0, 1024, 1);

  // ---- single mega-kernel runs the whole 128-step scan ----
  MegaArgs ma;
  ma.WbigF = WbigF; ma.WmsF = WmsF; ma.WkTF = WkTF;
  ma.WqF = WqF; ma.WvF = WvF; ma.WoF = WoF;
  ma.bmuF = bmuF; ma.bsigF = bsigF; ma.bkF = bkF;
  ma.bias4 = bias4; ma.bqk = bqk; ma.qbc = qbc; ma.bvo = bvo;
  ma.skeys = skeys; ma.gie4 = gie4;
  ma.xh = xh; ma.hbuf = hbuf; ma.gsumP = gsumP; ma.musigP = musigP;
  ma.qP = qP; ma.tmat = tmat; ma.qbv = qbv; ma.scg = scg;
  ma.ctxE = ctxE; ma.ctxhP = ctxhP; ma.ctxvP = ctxvP;
  ma.mus = mus; ma.sigs = sigs; ma.s = s;
  ma.bar = bar;
  megakernel<<<dim3(256), dim3(256), 0, stream>>>(ma);
  // d_out == s already holds step-127 sample (same fold_in(key,127) as eps_last)
}

// Round 5
// 85581.268 us; speedup vs baseline: 1.0204x; 1.0204x over previous
//
#include <hip/hip_runtime.h>

// Problem constants
#define B_   128
#define T_   128
#define E_   1024
#define H_   1024
#define A_   64
#define NH_  8
#define G_   3072
#define QK_  512
#define SCALE_ 0.125f
#define NBLK_ 256

// ---------------------------------------------------------------------------
// JAX Threefry-2x32-20 (bit-exact) + XLA f32 erfinv path
// ---------------------------------------------------------------------------
__device__ __forceinline__ unsigned rotl32(unsigned x, int r) {
  return (x << r) | (x >> (32 - r));
}

__device__ __forceinline__ void tf2x32(unsigned k0, unsigned k1,
                                       unsigned x0, unsigned x1,
                                       unsigned& o0, unsigned& o1) {
  unsigned k2 = k0 ^ k1 ^ 0x1BD11BDAu;
  x0 += k0; x1 += k1;
  x0 += x1; x1 = rotl32(x1, 13); x1 ^= x0;
  x0 += x1; x1 = rotl32(x1, 15); x1 ^= x0;
  x0 += x1; x1 = rotl32(x1, 26); x1 ^= x0;
  x0 += x1; x1 = rotl32(x1,  6); x1 ^= x0;
  x0 += k1; x1 += k2 + 1u;
  x0 += x1; x1 = rotl32(x1, 17); x1 ^= x0;
  x0 += x1; x1 = rotl32(x1, 29); x1 ^= x0;
  x0 += x1; x1 = rotl32(x1, 16); x1 ^= x0;
  x0 += x1; x1 = rotl32(x1, 24); x1 ^= x0;
  x0 += k2; x1 += k0 + 2u;
  x0 += x1; x1 = rotl32(x1, 13); x1 ^= x0;
  x0 += x1; x1 = rotl32(x1, 15); x1 ^= x0;
  x0 += x1; x1 = rotl32(x1, 26); x1 ^= x0;
  x0 += x1; x1 = rotl32(x1,  6); x1 ^= x0;
  x0 += k0; x1 += k1 + 3u;
  x0 += x1; x1 = rotl32(x1, 17); x1 ^= x0;
  x0 += x1; x1 = rotl32(x1, 29); x1 ^= x0;
  x0 += x1; x1 = rotl32(x1, 16); x1 ^= x0;
  x0 += x1; x1 = rotl32(x1, 24); x1 ^= x0;
  x0 += k1; x1 += k2 + 4u;
  x0 += x1; x1 = rotl32(x1, 13); x1 ^= x0;
  x0 += x1; x1 = rotl32(x1, 15); x1 ^= x0;
  x0 += x1; x1 = rotl32(x1, 26); x1 ^= x0;
  x0 += x1; x1 = rotl32(x1,  6); x1 ^= x0;
  x0 += k2; x1 += k0 + 5u;
  o0 = x0; o1 = x1;
}

__device__ __forceinline__ float bits_to_normal(unsigned bits) {
  float uf = __uint_as_float((bits >> 9) | 0x3F800000u) - 1.0f;
  const float LO = -0.99999994f;
  float u = fmaxf(LO, uf * 2.0f + LO);
  float w = -log1pf(-u * u);
  float p;
  if (w < 5.0f) {
    w -= 2.5f;
    p = 2.81022636e-08f;
    p = fmaf(p, w, 3.43273939e-07f);
    p = fmaf(p, w, -3.5233877e-06f);
    p = fmaf(p, w, -4.39150654e-06f);
    p = fmaf(p, w, 0.00021858087f);
    p = fmaf(p, w, -0.00125372503f);
    p = fmaf(p, w, -0.00417768164f);
    p = fmaf(p, w, 0.246640727f);
    p = fmaf(p, w, 1.50140941f);
  } else {
    w = sqrtf(w) - 3.0f;
    p = -0.000200214257f;
    p = fmaf(p, w, 0.000100950558f);
    p = fmaf(p, w, 0.00134934322f);
    p = fmaf(p, w, -0.00367342844f);
    p = fmaf(p, w, 0.00573950773f);
    p = fmaf(p, w, -0.0076224613f);
    p = fmaf(p, w, 0.00943887047f);
    p = fmaf(p, w, 1.00167406f);
    p = fmaf(p, w, 2.83297682f);
  }
  return 1.41421356f * p * u;
}

__device__ __forceinline__ float sigmoidf_(float x) {
  return 1.0f / (1.0f + expf(-x));
}

__device__ __forceinline__ float ld_elem(const void* p, long i, int isb) {
  if (isb) {
    unsigned short u = ((const unsigned short*)p)[i];
    return __uint_as_float(((unsigned)u) << 16);
  }
  return ((const float*)p)[i];
}

// ---------------------------------------------------------------------------
// Write-through (LLC-coherent) stores: sc0 sc1 make the store visible at
// device scope and keep the per-XCD L2 CLEAN, so the barrier's
// __threadfence (buffer_wbl2 + buffer_inv) finds nothing to write back.
// ---------------------------------------------------------------------------
typedef float f32x4_ __attribute__((ext_vector_type(4)));

__device__ __forceinline__ void stg1(float* p, float v) {
  asm volatile("global_store_dword %0, %1, off sc0 sc1"
               :: "v"(p), "v"(v) : "memory");
}
__device__ __forceinline__ void stg4(float* p, float4 v) {
  f32x4_ w; w.x = v.x; w.y = v.y; w.z = v.z; w.w = v.w;
  asm volatile("global_store_dwordx4 %0, %1, off sc0 sc1"
               :: "v"(p), "v"(w) : "memory");
}

// ---------------------------------------------------------------------------
// Grid barrier — EXACT structure that passed on-silicon in R2 (generation
// counter, __threadfence release/acquire).  The fences are now cheap because
// all inter-block stores are sc0sc1 (no dirty L2 lines to write back);
// buffer_inv still discards stale clean lines, which readers need anyway.
// ---------------------------------------------------------------------------
__device__ __forceinline__ void gsync(unsigned* bar) {
  asm volatile("s_waitcnt vmcnt(0)" ::: "memory");
  __syncthreads();
  if (threadIdx.x == 0) {
    __threadfence();  // release: (clean) wbl2 + inv
    unsigned g = __hip_atomic_load(&bar[1], __ATOMIC_RELAXED,
                                   __HIP_MEMORY_SCOPE_AGENT);
    unsigned a = __hip_atomic_fetch_add(&bar[0], 1u, __ATOMIC_ACQ_REL,
                                        __HIP_MEMORY_SCOPE_AGENT);
    if (a == NBLK_ - 1u) {
      __hip_atomic_store(&bar[0], 0u, __ATOMIC_RELAXED,
                         __HIP_MEMORY_SCOPE_AGENT);
      __hip_atomic_store(&bar[1], g + 1u, __ATOMIC_RELEASE,
                         __HIP_MEMORY_SCOPE_AGENT);
    } else {
      while (__hip_atomic_load(&bar[1], __ATOMIC_RELAXED,
                               __HIP_MEMORY_SCOPE_AGENT) == g) {
        __builtin_amdgcn_s_sleep(1);
      }
      __threadfence();  // acquire: invalidate stale caches
    }
  }
  __syncthreads();
}

// ---------------------------------------------------------------------------
// dtype sniffer + converter (verified).  sniff also zeroes the grid barrier.
// ---------------------------------------------------------------------------
__global__ __launch_bounds__(256) void sniff_kernel(const void* encs, int* flag) {
  __shared__ int cnt;
  if (threadIdx.x == 0) cnt = 0;
  if (threadIdx.x < 2) ((unsigned*)flag)[8 + threadIdx.x] = 0u;  // grid barrier
  __syncthreads();
  const unsigned* w = (const unsigned*)encs;
  int c = 0;
  for (int i = threadIdx.x; i < 4096; i += 256) {
    unsigned e7 = (w[i] >> 8) & 0x7F;
    if (e7 >= 0x3B && e7 <= 0x41) c++;
  }
  atomicAdd(&cnt, c);
  __syncthreads();
  if (threadIdx.x == 0) flag[0] = (cnt > 2048) ? 1 : 0;
}

__global__ __launch_bounds__(256) void conv_kernel(const void* src, float* dst,
                                                   long n, const int* flag) {
  long i = (long)blockIdx.x * 256 + threadIdx.x;
  int isb = flag[0];
  if (i < n) dst[i] = ld_elem(src, i, isb);
}

// ---------------------------------------------------------------------------
// trans: build Wbig (2048x4096 interleaved-4), Wms (1024x2048), WkT (512x1024),
// Wenc4 (1024x4096), bias4, zero xh/h, skeys.  grid (16384, 5)
// ---------------------------------------------------------------------------
__global__ __launch_bounds__(256) void trans_kernel(
    const void* W_ih, const void* W_hh, const void* W_mu, const void* W_sig,
    const void* W_k, const float* __restrict__ bihF, const float* __restrict__ bhhF,
    float* __restrict__ Wbig, float* __restrict__ Wms, float* __restrict__ WkT,
    float* __restrict__ Wenc4, float* __restrict__ bias4,
    float* __restrict__ xh, float* __restrict__ h, unsigned* __restrict__ skeys,
    const int* flag)
{
  long idx = (long)blockIdx.x * 256 + threadIdx.x;
  int y = blockIdx.y;
  int isb = flag[0];
  if (y == 0) {
    if (idx < 4194304) {
      int e = (int)(idx & 1023); int col = (int)(idx >> 10);
      int j = col >> 2, c = col & 3;
      float v = 0.f;
      if (c < 3) v = ld_elem(W_ih, (long)(c * 1024 + j) * 2048 + 1024 + e, isb);
      Wbig[(long)e * 4096 + col] = v;
    }
  } else if (y == 1) {
    if (idx < 4194304) {
      int e = (int)(idx & 1023); int col = (int)(idx >> 10);
      int j = col >> 2, c = col & 3;
      float v = 0.f;
      if (c == 0)      v = ld_elem(W_hh, (long)j * 1024 + e, isb);
      else if (c == 1) v = ld_elem(W_hh, (long)(1024 + j) * 1024 + e, isb);
      else if (c == 3) v = ld_elem(W_hh, (long)(2048 + j) * 1024 + e, isb);
      Wbig[(long)(1024 + e) * 4096 + col] = v;
    }
  } else if (y == 2) {
    if (idx < 2097152) {
      int k = (int)(idx >> 11), n = (int)(idx & 2047);
      float v = (n < 1024) ? ld_elem(W_mu, (long)k * 1024 + n, isb)
                           : ld_elem(W_sig, (long)k * 1024 + (n - 1024), isb);
      Wms[idx] = v;
    }
  } else if (y == 3) {
    if (idx < 524288) {
      int qk = (int)(idx >> 10), e = (int)(idx & 1023);
      WkT[idx] = ld_elem(W_k, (long)e * 512 + qk, isb);
    }
    if (idx < 4096) {
      int j = (int)(idx >> 2), c = (int)(idx & 3);
      float v;
      if (c == 0)      v = bihF[j] + bhhF[j];
      else if (c == 1) v = bihF[1024 + j] + bhhF[1024 + j];
      else if (c == 2) v = bihF[2048 + j];
      else             v = bhhF[2048 + j];
      bias4[idx] = v;
    }
    if (idx < 262144) xh[idx] = 0.f;
    if (idx < 131072) h[idx] = 0.f;
    if (idx < 128) {
      unsigned o0, o1;
      tf2x32(0u, 1234u, 0u, (unsigned)idx, o0, o1);
      skeys[2 * idx] = o0; skeys[2 * idx + 1] = o1;
    }
  } else {
    if (idx < 4194304) {
      int e = (int)(idx & 1023); int col = (int)(idx >> 10);
      int j = col >> 2, c = col & 3;
      float v = 0.f;
      if (c < 3) v = ld_elem(W_ih, (long)(c * 1024 + j) * 2048 + e, isb);
      Wenc4[(long)e * 4096 + col] = v;
    }
  }
}

// ---------------------------------------------------------------------------
// consts: bqk[h][e], qbc[h], bvo[e].  grid (32)
// ---------------------------------------------------------------------------
__global__ __launch_bounds__(256) void consts_kernel(
    const float* __restrict__ bqF, const float* __restrict__ bkF,
    const float* __restrict__ bvF, const float* __restrict__ boF,
    const float* __restrict__ WkT, const float* __restrict__ WoF,
    float* __restrict__ bqk, float* __restrict__ qbc, float* __restrict__ bvo)
{
  int idx = blockIdx.x * 256 + threadIdx.x;
  int hh = idx >> 10, e = idx & 1023;
  float s = 0.f;
  for (int a = 0; a < 64; ++a)
    s += bqF[hh * 64 + a] * WkT[(long)(hh * 64 + a) * 1024 + e];
  bqk[idx] = s;
  if (idx < 1024) {
    float v = boF[idx];
    for (int ha = 0; ha < 512; ++ha) v += bvF[ha] * WoF[(long)ha * 1024 + idx];
    bvo[idx] = v;
  }
  if (idx < 8) {
    float v = 0.f;
    for (int a = 0; a < 64; ++a) v += bqF[idx * 64 + a] * bkF[idx * 64 + a];
    qbc[idx] = v;
  }
}

// ---------------------------------------------------------------------------
// Mega-kernel argument block
// ---------------------------------------------------------------------------
struct MegaArgs {
  const float *WbigF, *WmsF, *WkTF, *WqF, *WvF, *WoF;
  const float *bmuF, *bsigF, *bkF, *bias4, *bqk, *qbc, *bvo;
  const unsigned *skeys;
  const float *gie4;
  float *xh, *hbuf, *gsumP, *musigP, *qP, *tmat, *qbv, *scg;
  float *ctxE, *ctxhP, *ctxvP, *mus, *sigs, *s;
  unsigned *bar;
};

// ---------------------------------------------------------------------------
// mm128 device: 128x128 tile, 8x8/thread, split-K partial store.
// ---------------------------------------------------------------------------
__device__ void mm128_dev(float* smem,
    const float* A, long lda, long zA, int nsumA, long psA,
    const float* Bm, long ldb, long zB,
    float* C, long ldc, long zC, long pstride,
    int Ktot, int S, int bx, int by, int zz, int tid)
{
  int head = zz / S, sp = zz - head * S;
  int Kc = Ktot / S;
  long kb = (long)sp * Kc;
  A += (long)head * zA;
  Bm += (long)head * zB;
  C += (long)head * zC + (long)sp * pstride;
  long m0 = (long)by * 128;
  long n0 = (long)bx * 128;
  float* As = smem;            // [16][132]
  float* Bs = smem + 2112;     // [16][132]
  int tx = tid & 15, ty = tid >> 4;
  int am = tid >> 2, ac = tid & 3;
  int bk = tid >> 5, bn = tid & 31;
  float acc[8][8];
  #pragma unroll
  for (int i = 0; i < 8; ++i)
    #pragma unroll
    for (int j = 0; j < 8; ++j) acc[i][j] = 0.f;

  for (int k0 = 0; k0 < Kc; k0 += 16) {
    const float* Ap0 = A + (m0 + am) * lda + kb + k0 + 4 * ac;
    const float* Ap1 = A + (m0 + am + 64) * lda + kb + k0 + 4 * ac;
    float4 a0 = *(const float4*)Ap0;
    float4 a1 = *(const float4*)Ap1;
    for (int s2 = 1; s2 < nsumA; ++s2) {
      float4 t0 = *(const float4*)(Ap0 + (long)s2 * psA);
      float4 t1 = *(const float4*)(Ap1 + (long)s2 * psA);
      a0.x += t0.x; a0.y += t0.y; a0.z += t0.z; a0.w += t0.w;
      a1.x += t1.x; a1.y += t1.y; a1.z += t1.z; a1.w += t1.w;
    }
    float4 b0 = *(const float4*)(Bm + (kb + k0 + bk) * ldb + n0 + 4 * bn);
    float4 b1 = *(const float4*)(Bm + (kb + k0 + bk + 8) * ldb + n0 + 4 * bn);
    __syncthreads();
    As[(4 * ac + 0) * 132 + am] = a0.x; As[(4 * ac + 1) * 132 + am] = a0.y;
    As[(4 * ac + 2) * 132 + am] = a0.z; As[(4 * ac + 3) * 132 + am] = a0.w;
    As[(4 * ac + 0) * 132 + am + 64] = a1.x; As[(4 * ac + 1) * 132 + am + 64] = a1.y;
    As[(4 * ac + 2) * 132 + am + 64] = a1.z; As[(4 * ac + 3) * 132 + am + 64] = a1.w;
    *(float4*)&Bs[bk * 132 + 4 * bn] = b0;
    *(float4*)&Bs[(bk + 8) * 132 + 4 * bn] = b1;
    __syncthreads();
    #pragma unroll
    for (int kk = 0; kk < 16; ++kk) {
      float4 av0 = *(const float4*)&As[kk * 132 + ty * 4];
      float4 av1 = *(const float4*)&As[kk * 132 + 64 + ty * 4];
      float4 bv0 = *(const float4*)&Bs[kk * 132 + tx * 4];
      float4 bv1 = *(const float4*)&Bs[kk * 132 + 64 + tx * 4];
      float amv[8] = {av0.x, av0.y, av0.z, av0.w, av1.x, av1.y, av1.z, av1.w};
      float bnv[8] = {bv0.x, bv0.y, bv0.z, bv0.w, bv1.x, bv1.y, bv1.z, bv1.w};
      #pragma unroll
      for (int i = 0; i < 8; ++i)
        #pragma unroll
        for (int j = 0; j < 8; ++j)
          acc[i][j] = fmaf(amv[i], bnv[j], acc[i][j]);
    }
  }

  #pragma unroll
  for (int i = 0; i < 8; ++i) {
    long r = m0 + (long)(i >> 2) * 64 + ty * 4 + (i & 3);
    float4 v0 = {acc[i][0], acc[i][1], acc[i][2], acc[i][3]};
    float4 v1 = {acc[i][4], acc[i][5], acc[i][6], acc[i][7]};
    stg4(C + r * ldc + n0 + tx * 4, v0);
    stg4(C + r * ldc + n0 + 64 + tx * 4, v1);
  }
}

// ---------------------------------------------------------------------------
// mm64s device: 64x64 tile, 4x4/thread, split-K partial store, A can sum nsumA
// ---------------------------------------------------------------------------
__device__ void mm64s_dev(float* smem,
    const float* A, long lda, long zA, int nsumA, long psA,
    const float* Bm, long ldb, long zB,
    float* C, long ldc, long zC, long pstride,
    int Ktot, int S, int bx, int by, int zz, int tid)
{
  int head = zz / S, sp = zz - head * S;
  int Kc = Ktot / S;
  long kb = (long)sp * Kc;
  A += (long)head * zA; Bm += (long)head * zB;
  C += (long)head * zC + (long)sp * pstride;
  long n0 = (long)bx * 64;
  long m0 = (long)by * 64;
  float* As = smem;            // [16][68]
  float* Bs = smem + 1088;     // [16][68]
  int tx = tid & 15, ty = tid >> 4;
  int ar = tid >> 2, ac = tid & 3;
  int br = tid >> 4, bc = tid & 15;
  float acc[4][4];
  #pragma unroll
  for (int i = 0; i < 4; ++i)
    #pragma unroll
    for (int j = 0; j < 4; ++j) acc[i][j] = 0.f;

  for (int k0 = 0; k0 < Kc; k0 += 16) {
    const float* Ap = A + (m0 + ar) * lda + kb + k0 + 4 * ac;
    float4 a4 = *(const float4*)Ap;
    for (int s2 = 1; s2 < nsumA; ++s2) {
      float4 t = *(const float4*)(Ap + (long)s2 * psA);
      a4.x += t.x; a4.y += t.y; a4.z += t.z; a4.w += t.w;
    }
    float4 b4 = *(const float4*)(Bm + (kb + k0 + br) * ldb + n0 + 4 * bc);
    __syncthreads();
    As[(4 * ac + 0) * 68 + ar] = a4.x; As[(4 * ac + 1) * 68 + ar] = a4.y;
    As[(4 * ac + 2) * 68 + ar] = a4.z; As[(4 * ac + 3) * 68 + ar] = a4.w;
    *(float4*)(&Bs[br * 68 + 4 * bc]) = b4;
    __syncthreads();
    #pragma unroll
    for (int kk = 0; kk < 16; ++kk) {
      float4 av = *(const float4*)(&As[kk * 68 + 4 * ty]);
      float4 bv = *(const float4*)(&Bs[kk * 68 + 4 * tx]);
      float amv[4] = {av.x, av.y, av.z, av.w};
      float bnv[4] = {bv.x, bv.y, bv.z, bv.w};
      #pragma unroll
      for (int im = 0; im < 4; ++im)
        #pragma unroll
        for (int jn = 0; jn < 4; ++jn)
          acc[im][jn] = fmaf(amv[im], bnv[jn], acc[im][jn]);
    }
  }
  #pragma unroll
  for (int im = 0; im < 4; ++im) {
    long m = m0 + ty * 4 + im;
    float4 v = {acc[im][0], acc[im][1], acc[im][2], acc[im][3]};
    stg4(C + m * ldc + n0 + tx * 4, v);
  }
}

// ---------------------------------------------------------------------------
// GRU epilogue (per virtual index)
// ---------------------------------------------------------------------------
__device__ void gru_dev(int idx, const MegaArgs& a) {
  int b = idx >> 10, j = idx & 1023;
  float4 v = ((const float4*)a.gie4)[(long)b * 1024 + j];
  float4 bb4 = ((const float4*)a.bias4)[j];
  v.x += bb4.x; v.y += bb4.y; v.z += bb4.z; v.w += bb4.w;
  #pragma unroll
  for (int s2 = 0; s2 < 8; ++s2) {
    float4 t = ((const float4*)a.gsumP)[(long)s2 * 131072 + (long)b * 1024 + j];
    v.x += t.x; v.y += t.y; v.z += t.z; v.w += t.w;
  }
  float r = sigmoidf_(v.x);
  float z = sigmoidf_(v.y);
  float n = tanhf(v.z + r * v.w);
  float ho = a.hbuf[idx];
  float hn = (1.0f - z) * n + z * ho;
  stg1(a.hbuf + idx, hn);
  stg1(a.xh + (long)b * 2048 + 1024 + j, hn);
}

// ---------------------------------------------------------------------------
// Fused mu/sig epilogue + gen of s row `step` (2 elements per thread)
// ---------------------------------------------------------------------------
__device__ void musig_gen_dev(int bid, int tid, int step, const MegaArgs& a) {
  unsigned sk0 = a.skeys[2 * step], sk1 = a.skeys[2 * step + 1];
  #pragma unroll
  for (int k = 0; k < 2; ++k) {
    int el = bid * 256 + tid + k * 65536;
    int b = el >> 10, e = el & 1023;
    float mu = a.bmuF[e], xg = a.bsigF[e];
    #pragma unroll
    for (int s2 = 0; s2 < 8; ++s2) {
      mu += a.musigP[(long)s2 * 262144 + (long)b * 2048 + e];
      xg += a.musigP[(long)s2 * 262144 + (long)b * 2048 + 1024 + e];
    }
    float sig = fmaxf(xg, 0.0f) + log1pf(expf(-fabsf(xg)));
    stg1(a.mus + ((long)b * T_ + step) * E_ + e, mu);
    stg1(a.sigs + ((long)b * T_ + step) * E_ + e, sig);
    unsigned f = (unsigned)(b * (T_ * E_) + step * E_ + e);
    unsigned o0, o1;
    tf2x32(sk0, sk1, 0u, f, o0, o1);
    stg1(a.s + ((long)b * T_ + step) * E_ + e,
         fmaf(bits_to_normal(o0 ^ o1), sig, mu));
  }
}

// ---------------------------------------------------------------------------
// gen_s rows [lo, hi) with step-`step` keys, distributed across nb blocks
// ---------------------------------------------------------------------------
__device__ void gen_rows_dev(int lo, int hi, int lbid, int nb, int step,
                             const MegaArgs& a, int tid) {
  int nvb = (hi - lo) * 128;
  if (nvb <= 0) return;
  unsigned sk0 = a.skeys[2 * step], sk1 = a.skeys[2 * step + 1];
  for (int vb = lbid; vb < nvb; vb += nb) {
    int t = lo + (vb >> 7);
    int b = vb & 127;
    int e = tid * 4;
    unsigned f = (unsigned)(b * (T_ * E_) + t * E_ + e);
    unsigned o0, o1;
    float nv[4];
    tf2x32(sk0, sk1, 0u, f + 0u, o0, o1); nv[0] = bits_to_normal(o0 ^ o1);
    tf2x32(sk0, sk1, 0u, f + 1u, o0, o1); nv[1] = bits_to_normal(o0 ^ o1);
    tf2x32(sk0, sk1, 0u, f + 2u, o0, o1); nv[2] = bits_to_normal(o0 ^ o1);
    tf2x32(sk0, sk1, 0u, f + 3u, o0, o1); nv[3] = bits_to_normal(o0 ^ o1);
    long i4 = (((long)b * T_ + t) * E_ + e) >> 2;
    float4 mu = ((const float4*)a.mus)[i4];
    float4 sg = ((const float4*)a.sigs)[i4];
    float4 out;
    out.x = fmaf(nv[0], sg.x, mu.x);
    out.y = fmaf(nv[1], sg.y, mu.y);
    out.z = fmaf(nv[2], sg.z, mu.z);
    out.w = fmaf(nv[3], sg.w, mu.w);
    stg4(a.s + i4 * 4, out);
  }
}

// ---------------------------------------------------------------------------
// t-matrix
// ---------------------------------------------------------------------------
__device__ void tk_dev(float* smem, int vb, const MegaArgs& a, int tid) {
  int bx = vb & 3, hh = (vb >> 2) & 7, bz = vb >> 5;
  int e = bx * 256 + tid;
  int b0 = bz * 8;
  float* q_l = smem;  // [8][64]
  __syncthreads();
  for (int idx2 = tid; idx2 < 512; idx2 += 256) {
    int bb = idx2 >> 6, aa = idx2 & 63;
    float v = 0.f;
    #pragma unroll
    for (int s2 = 0; s2 < 8; ++s2)
      v += a.qP[(long)s2 * 65536 + (long)(b0 + bb) * 512 + hh * 64 + aa];
    q_l[bb * 64 + aa] = v;
  }
  __syncthreads();
  float acc[8];
  #pragma unroll
  for (int bb = 0; bb < 8; ++bb) acc[bb] = 0.f;
  for (int aa = 0; aa < 64; ++aa) {
    float wv = a.WkTF[(long)(hh * 64 + aa) * 1024 + e];
    #pragma unroll
    for (int bb = 0; bb < 8; ++bb) acc[bb] = fmaf(q_l[bb * 64 + aa], wv, acc[bb]);
  }
  float bq_ = a.bqk[hh * 1024 + e];
  #pragma unroll
  for (int bb = 0; bb < 8; ++bb)
    stg1(a.tmat + ((long)(b0 + bb) * NH_ + hh) * 1024 + e, acc[bb] + bq_);
  if (bx == 0 && tid < 8) {
    int bb = tid;
    float sm2 = a.qbc[hh];
    for (int aa = 0; aa < 64; ++aa) sm2 += q_l[bb * 64 + aa] * a.bkF[hh * 64 + aa];
    stg1(a.qbv + (b0 + bb) * NH_ + hh, sm2);
  }
}

// ---------------------------------------------------------------------------
// scores
// ---------------------------------------------------------------------------
__device__ void sc_dev(float* smem, int jt, int b, int step, const MegaArgs& a,
                       int tid) {
  int jbase = jt * 32;
  float* s_ch = smem;            // [32][132]
  float* t_ch = smem + 32 * 132; // [8][132]
  int hh = tid >> 5, jj = tid & 31;
  int j = jbase + jj;
  float acc = 0.f;
  for (int e0 = 0; e0 < 1024; e0 += 128) {
    __syncthreads();
    #pragma unroll
    for (int q = 0; q < 4; ++q) {
      int f = tid + q * 256;
      int jr = f >> 5, e4 = f & 31;
      int jg = jbase + jr;
      if (jg <= step)
        *(float4*)&s_ch[jr * 132 + e4 * 4] =
            *(const float4*)&a.s[((long)b * T_ + jg) * E_ + e0 + e4 * 4];
    }
    {
      int e4 = tid & 31, h2 = tid >> 5;
      *(float4*)&t_ch[h2 * 132 + e4 * 4] =
          *(const float4*)&a.tmat[((long)b * NH_ + h2) * E_ + e0 + e4 * 4];
    }
    __syncthreads();
    if (j <= step) {
      #pragma unroll
      for (int e4 = 0; e4 < 32; ++e4) {
        float4 sv = *(const float4*)&s_ch[jj * 132 + e4 * 4];
        float4 tv = *(const float4*)&t_ch[hh * 132 + e4 * 4];
        acc = fmaf(sv.x, tv.x, acc);
        acc = fmaf(sv.y, tv.y, acc);
        acc = fmaf(sv.z, tv.z, acc);
        acc = fmaf(sv.w, tv.w, acc);
      }
    }
  }
  if (j <= step)
    stg1(a.scg + ((long)b * NH_ + hh) * T_ + j,
         (acc + a.qbv[b * NH_ + hh]) * SCALE_);
}

// ---------------------------------------------------------------------------
// softmax + ctx
// ---------------------------------------------------------------------------
__device__ void ctx_dev(float* smem, int et, int b, int step, const MegaArgs& a,
                        int tid) {
  float* w_l = smem;         // [8][128]
  float* s_l = smem + 1024;  // [32][68]
  __syncthreads();
  {
    int hh = tid >> 5, l = tid & 31;
    const float* sc = a.scg + ((long)b * NH_ + hh) * T_;
    float m = -3.0e38f;
    for (int j = l; j <= step; j += 32) m = fmaxf(m, sc[j]);
    for (int off = 16; off; off >>= 1) m = fmaxf(m, __shfl_xor(m, off, 32));
    float d = 0.f;
    for (int j = l; j <= step; j += 32) {
      float pe = expf(sc[j] - m);
      w_l[hh * T_ + j] = pe;
      d += pe;
    }
    for (int off = 16; off; off >>= 1) d += __shfl_xor(d, off, 32);
    float inv = 1.0f / d;
    for (int j = l; j <= step; j += 32) w_l[hh * T_ + j] *= inv;
  }
  int e = tid & 63, hp = tid >> 6;
  float acc0 = 0.f, acc1 = 0.f;
  for (int jc = 0; jc <= step; jc += 32) {
    __syncthreads();
    #pragma unroll
    for (int q = 0; q < 8; ++q) {
      int f = tid + q * 256;
      int jr = f >> 6, ee = f & 63;
      int jg = jc + jr;
      if (jg <= step)
        s_l[jr * 68 + ee] = a.s[((long)b * T_ + jg) * E_ + et * 64 + ee];
    }
    __syncthreads();
    int jmax = min(31, step - jc);
    for (int jr = 0; jr <= jmax; ++jr) {
      float sv = s_l[jr * 68 + e];
      acc0 = fmaf(w_l[hp * T_ + jc + jr], sv, acc0);
      acc1 = fmaf(w_l[(hp + 4) * T_ + jc + jr], sv, acc1);
    }
  }
  stg1(a.ctxE + ((long)b * NH_ + hp) * E_ + et * 64 + e, acc0);
  stg1(a.ctxE + ((long)b * NH_ + hp + 4) * E_ + et * 64 + e, acc1);
}

// ---------------------------------------------------------------------------
// finalize xh ctx half (sums 8 O partials)
// ---------------------------------------------------------------------------
__device__ void fin_dev(int vb, int tid, const MegaArgs& a) {
  int i4 = vb * 256 + tid;  // < 32768 float4s
  int b = i4 >> 8, e4 = i4 & 255;
  float4 v = ((const float4*)a.bvo)[e4];
  #pragma unroll
  for (int s2 = 0; s2 < 8; ++s2) {
    float4 t = ((const float4*)a.ctxvP)[(long)s2 * 32768 + (long)b * 256 + e4];
    v.x += t.x; v.y += t.y; v.z += t.z; v.w += t.w;
  }
  stg4(a.xh + ((long)b * 512 + e4) * 4, v);
}

// ---------------------------------------------------------------------------
// Prep-only standalone mm128 wrapper (for gie4 = encs @ Wenc4)
// ---------------------------------------------------------------------------
__global__ __launch_bounds__(256) void mm128_k(
    const float* A, long lda, long zA, int nsumA, long psA,
    const float* Bm, long ldb, long zB,
    float* C, long ldc, long zC, long pstride, int Ktot, int S)
{
  __shared__ __align__(16) float smem[4224];
  mm128_dev(smem, A, lda, zA, nsumA, psA, Bm, ldb, zB, C, ldc, zC, pstride,
            Ktot, S, blockIdx.x, blockIdx.y, blockIdx.z, threadIdx.x);
}

// ---------------------------------------------------------------------------
// THE mega-kernel: whole 128-step scan, plain launch (graph-capture safe),
// 256 blocks x 256 threads (1 block/CU — R2-proven co-resident geometry),
// R2-proven grid barrier + sc0sc1 write-through stores (cheap fences),
// 11 syncs per step.  gen_s of rows < i overlaps G1/G2/Q phases.
// ---------------------------------------------------------------------------
__global__ __launch_bounds__(256) void megakernel(MegaArgs a) {
  const int bid = blockIdx.x;
  const int tid = threadIdx.x;
  unsigned* bar = a.bar;
  __shared__ __align__(16) float smem[5280];

  #pragma unroll 1
  for (int i = 0; i < T_; ++i) {
    int r1 = (i * 7) / 12;   // gen rows [0,r1) in P1
    int r2 = (i * 10) / 12;  // gen rows [r1,r2) in P3, [r2,i) in P5
    // P1: G1 partials (256 subs: 32 n-tiles x 8 k-splits) + gen_s [0,r1)
    mm128_dev(smem, a.xh, 2048, 0, 1, 0, a.WbigF, 4096, 0,
              a.gsumP, 4096, 0, 524288, 2048, 8, bid & 31, 0, bid >> 5, tid);
    gen_rows_dev(0, r1, bid, 256, i, a, tid);
    gsync(bar);
    // P2: GRU epilogue (512 vblocks, 2 per block)
    gru_dev(bid * 256 + tid, a);
    gru_dev((bid + 256) * 256 + tid, a);
    gsync(bar);
    // P3: G2 partials (128 subs) on blocks <128; gen_s on the other 128
    if (bid < 128)
      mm128_dev(smem, a.hbuf, 1024, 0, 1, 0, a.WmsF, 2048, 0,
                a.musigP, 2048, 0, 262144, 1024, 8, bid & 15, 0, bid >> 4, tid);
    else
      gen_rows_dev(r1, r2, bid - 128, 128, i, a, tid);
    gsync(bar);
    // P4: fused mu/sig epilogue + gen of s row i (all blocks, 2 elem/thread)
    musig_gen_dev(bid, tid, i, a);
    gsync(bar);
    // P5: Q partials (128 subs) on blocks <128; gen_s on the other 128
    if (bid < 128)
      mm64s_dev(smem, a.s + (long)i * E_, (long)T_ * E_, 0, 1, 0,
                a.WqF, 512, 0, a.qP, 512, 0, 65536, 1024, 8,
                bid & 7, (bid >> 3) & 1, bid >> 4, tid);
    else
      gen_rows_dev(r2, i, bid - 128, 128, i, a, tid);
    gsync(bar);
    // P6: t-matrix (512 vblocks, 2 per block)
    for (int vb = bid; vb < 512; vb += NBLK_) tk_dev(smem, vb, a, tid);
    gsync(bar);
    // P7: scores
    {
      int nvb = ((i + 32) / 32) * 128;
      for (int vb = bid; vb < nvb; vb += NBLK_)
        sc_dev(smem, vb >> 7, vb & 127, i, a, tid);
    }
    gsync(bar);
    // P8: softmax + ctx (2048 vblocks, 8 per block)
    for (int vb = bid; vb < 2048; vb += NBLK_)
      ctx_dev(smem, vb & 15, vb >> 4, i, a, tid);
    gsync(bar);
    // P9: V partials (64 subs, per-head K=1024 split-4)
    if (bid < 64)
      mm64s_dev(smem, a.ctxE, 8192, 1024, 1, 0, a.WvF, 512, 64,
                a.ctxhP, 512, 64, 65536, 1024, 4, 0, bid & 1, bid >> 1, tid);
    gsync(bar);
    // P10: O partials (256 subs: 16n x 2m x 8k, sums 4 V partials)
    mm64s_dev(smem, a.ctxhP, 512, 0, 4, 65536, a.WoF, 1024, 0,
              a.ctxvP, 1024, 0, 131072, 512, 8,
              bid & 15, (bid >> 4) & 1, bid >> 5, tid);
    gsync(bar);
    // P11: finalize xh ctx half
    if (bid < 128) fin_dev(bid, tid, a);
    gsync(bar);
  }
}

// ---------------------------------------------------------------------------
// Host side
// ---------------------------------------------------------------------------
extern "C" void kernel_launch(void* const* d_in, const int* in_sizes, int n_in,
                              void* d_out, int out_size, void* d_ws, size_t ws_size,
                              hipStream_t stream) {
  (void)in_sizes; (void)n_in; (void)out_size; (void)ws_size;
  const void* encs  = d_in[0];
  const void* W_ih  = d_in[1];
  const void* W_hh  = d_in[2];
  const void* b_ih  = d_in[3];
  const void* b_hh  = d_in[4];
  const void* W_mu  = d_in[5];
  const void* b_mu  = d_in[6];
  const void* W_sig = d_in[7];
  const void* b_sig = d_in[8];
  const void* W_q   = d_in[9];
  const void* b_q   = d_in[10];
  const void* W_k   = d_in[11];
  const void* b_k   = d_in[12];
  const void* W_v   = d_in[13];
  const void* b_v   = d_in[14];
  const void* W_o   = d_in[15];
  const void* b_o   = d_in[16];

  float* s = (float*)d_out;
  float* w = (float*)d_ws;

  int*   flag   = (int*)w;
  unsigned* bar = ((unsigned*)w) + 8;   // bar[0]=arrive, bar[1]=gen
  float* p      = w + 1024;
  float* WbigF  = p;  p += (size_t)2048 * 4096;
  float* WmsF   = p;  p += (size_t)1024 * 2048;
  float* WkTF   = p;  p += (size_t)512 * 1024;
  float* WqF    = p;  p += (size_t)1024 * 512;
  float* WvF    = p;  p += (size_t)1024 * 512;
  float* WoF    = p;  p += (size_t)512 * 1024;
  float* encsF  = p;  p += (size_t)B_ * E_;
  float* bihF   = p;  p += 4096;
  float* bhhF   = p;  p += 4096;
  float* bmuF   = p;  p += 1024;
  float* bsigF  = p;  p += 1024;
  float* bqF    = p;  p += 1024;
  float* bkF    = p;  p += 1024;
  float* bvF    = p;  p += 1024;
  float* boF    = p;  p += 1024;
  float* bias4  = p;  p += 4096;
  float* bqk    = p;  p += 8192;
  float* qbc    = p;  p += 1024;
  float* bvo    = p;  p += 1024;
  unsigned* skeys = (unsigned*)p; p += 1024;
  float* gie4   = p;  p += (size_t)B_ * 4096;
  float* xh     = p;  p += (size_t)B_ * 2048;     // [ctx | h]
  float* hbuf   = p;  p += (size_t)B_ * 1024;
  float* gsumP  = p;  p += (size_t)8 * B_ * 4096; // aliased: Wenc4 (prep), ctxvP (P10/P11)
  float* musigP = p;  p += (size_t)8 * B_ * 2048;
  float* qP     = p;  p += (size_t)8 * B_ * 512;
  float* tmat   = p;  p += (size_t)B_ * NH_ * E_;
  float* qbv    = p;  p += 1024;
  float* scg    = p;  p += (size_t)B_ * NH_ * T_;
  float* ctxE   = p;  p += (size_t)B_ * NH_ * E_;
  float* ctxhP  = p;  p += (size_t)4 * B_ * 512;
  float* mus    = p;  p += (size_t)B_ * T_ * E_;
  float* sigs   = p;  p += (size_t)B_ * T_ * E_;
  float* Wenc4  = gsumP;  // prep-only alias (consumed before first G1 write)
  float* ctxvP  = gsumP;  // in-loop alias: gsumP is dead between P2 and next P1

  // ---- prep ----
  sniff_kernel<<<1, 256, 0, stream>>>(encs, flag);
  auto conv = [&](const void* src, float* dst, long n) {
    conv_kernel<<<dim3((unsigned)((n + 255) / 256)), 256, 0, stream>>>(src, dst, n, flag);
  };
  conv(encs,  encsF, (long)B_ * E_);
  conv(b_ih,  bihF,  G_);
  conv(b_hh,  bhhF,  G_);
  conv(b_mu,  bmuF,  1024);
  conv(b_sig, bsigF, 1024);
  conv(b_q,   bqF,   512);
  conv(b_k,   bkF,   512);
  conv(b_v,   bvF,   512);
  conv(b_o,   boF,   1024);
  conv(W_q,   WqF,   (long)1024 * 512);
  conv(W_v,   WvF,   (long)1024 * 512);
  conv(W_o,   WoF,   (long)512 * 1024);

  trans_kernel<<<dim3(16384, 5), 256, 0, stream>>>(
      W_ih, W_hh, W_mu, W_sig, W_k, bihF, bhhF,
      WbigF, WmsF, WkTF, Wenc4, bias4, xh, hbuf, skeys, flag);
  consts_kernel<<<dim3(32), 256, 0, stream>>>(
      bqF, bkF, bvF, boF, WkTF, WoF, bqk, qbc, bvo);
  // gie4 = encs @ Wenc4  (reads the gsumP-aliased Wenc4 BEFORE the loop)
  mm128_k<<<dim3(32, 1, 1), 256, 0, stream>>>(
      encsF, 1024, 0, 1, 0, Wenc4, 4096, 0, gie4, 4096, 0, 0, 1024, 1);

  // ---- single mega-kernel runs the whole 128-step scan ----
  MegaArgs ma;
  ma.WbigF = WbigF; ma.WmsF = WmsF; ma.WkTF = WkTF;
  ma.WqF = WqF; ma.WvF = WvF; ma.WoF = WoF;
  ma.bmuF = bmuF; ma.bsigF = bsigF; ma.bkF = bkF;
  ma.bias4 = bias4; ma.bqk = bqk; ma.qbc = qbc; ma.bvo = bvo;
  ma.skeys = skeys; ma.gie4 = gie4;
  ma.xh = xh; ma.hbuf = hbuf; ma.gsumP = gsumP; ma.musigP = musigP;
  ma.qP = qP; ma.tmat = tmat; ma.qbv = qbv; ma.scg = scg;
  ma.ctxE = ctxE; ma.ctxhP = ctxhP; ma.ctxvP = ctxvP;
  ma.mus = mus; ma.sigs = sigs; ma.s = s;
  ma.bar = bar;
  megakernel<<<dim3(NBLK_), dim3(256), 0, stream>>>(ma);
  // d_out == s already holds step-127 sample (same fold_in(key,127) as eps_last)
}

// Round 6
// 38746.063 us; speedup vs baseline: 2.2539x; 2.2088x over previous
//
#include <hip/hip_runtime.h>

// Problem constants
#define B_   128
#define T_   128
#define E_   1024
#define H_   1024
#define A_   64
#define NH_  8
#define G_   3072
#define QK_  512
#define SCALE_ 0.125f

// ---------------------------------------------------------------------------
// JAX Threefry-2x32-20 (bit-exact) + XLA f32 erfinv path
// ---------------------------------------------------------------------------
__device__ __forceinline__ unsigned rotl32(unsigned x, int r) {
  return (x << r) | (x >> (32 - r));
}

__device__ __forceinline__ void tf2x32(unsigned k0, unsigned k1,
                                       unsigned x0, unsigned x1,
                                       unsigned& o0, unsigned& o1) {
  unsigned k2 = k0 ^ k1 ^ 0x1BD11BDAu;
  x0 += k0; x1 += k1;
  x0 += x1; x1 = rotl32(x1, 13); x1 ^= x0;
  x0 += x1; x1 = rotl32(x1, 15); x1 ^= x0;
  x0 += x1; x1 = rotl32(x1, 26); x1 ^= x0;
  x0 += x1; x1 = rotl32(x1,  6); x1 ^= x0;
  x0 += k1; x1 += k2 + 1u;
  x0 += x1; x1 = rotl32(x1, 17); x1 ^= x0;
  x0 += x1; x1 = rotl32(x1, 29); x1 ^= x0;
  x0 += x1; x1 = rotl32(x1, 16); x1 ^= x0;
  x0 += x1; x1 = rotl32(x1, 24); x1 ^= x0;
  x0 += k2; x1 += k0 + 2u;
  x0 += x1; x1 = rotl32(x1, 13); x1 ^= x0;
  x0 += x1; x1 = rotl32(x1, 15); x1 ^= x0;
  x0 += x1; x1 = rotl32(x1, 26); x1 ^= x0;
  x0 += x1; x1 = rotl32(x1,  6); x1 ^= x0;
  x0 += k0; x1 += k1 + 3u;
  x0 += x1; x1 = rotl32(x1, 17); x1 ^= x0;
  x0 += x1; x1 = rotl32(x1, 29); x1 ^= x0;
  x0 += x1; x1 = rotl32(x1, 16); x1 ^= x0;
  x0 += x1; x1 = rotl32(x1, 24); x1 ^= x0;
  x0 += k1; x1 += k2 + 4u;
  x0 += x1; x1 = rotl32(x1, 13); x1 ^= x0;
  x0 += x1; x1 = rotl32(x1, 15); x1 ^= x0;
  x0 += x1; x1 = rotl32(x1, 26); x1 ^= x0;
  x0 += x1; x1 = rotl32(x1,  6); x1 ^= x0;
  x0 += k2; x1 += k0 + 5u;
  o0 = x0; o1 = x1;
}

__device__ __forceinline__ float bits_to_normal(unsigned bits) {
  float uf = __uint_as_float((bits >> 9) | 0x3F800000u) - 1.0f;
  const float LO = -0.99999994f;
  float u = fmaxf(LO, uf * 2.0f + LO);
  float w = -log1pf(-u * u);
  float p;
  if (w < 5.0f) {
    w -= 2.5f;
    p = 2.81022636e-08f;
    p = fmaf(p, w, 3.43273939e-07f);
    p = fmaf(p, w, -3.5233877e-06f);
    p = fmaf(p, w, -4.39150654e-06f);
    p = fmaf(p, w, 0.00021858087f);
    p = fmaf(p, w, -0.00125372503f);
    p = fmaf(p, w, -0.00417768164f);
    p = fmaf(p, w, 0.246640727f);
    p = fmaf(p, w, 1.50140941f);
  } else {
    w = sqrtf(w) - 3.0f;
    p = -0.000200214257f;
    p = fmaf(p, w, 0.000100950558f);
    p = fmaf(p, w, 0.00134934322f);
    p = fmaf(p, w, -0.00367342844f);
    p = fmaf(p, w, 0.00573950773f);
    p = fmaf(p, w, -0.0076224613f);
    p = fmaf(p, w, 0.00943887047f);
    p = fmaf(p, w, 1.00167406f);
    p = fmaf(p, w, 2.83297682f);
  }
  return 1.41421356f * p * u;
}

__device__ __forceinline__ float sigmoidf_(float x) {
  return 1.0f / (1.0f + expf(-x));
}

__device__ __forceinline__ float ld_elem(const void* p, long i, int isb) {
  if (isb) {
    unsigned short u = ((const unsigned short*)p)[i];
    return __uint_as_float(((unsigned)u) << 16);
  }
  return ((const float*)p)[i];
}

// ---------------------------------------------------------------------------
// dtype sniffer + converter (verified)
// ---------------------------------------------------------------------------
__global__ __launch_bounds__(256) void sniff_kernel(const void* encs, int* flag) {
  __shared__ int cnt;
  if (threadIdx.x == 0) cnt = 0;
  __syncthreads();
  const unsigned* w = (const unsigned*)encs;
  int c = 0;
  for (int i = threadIdx.x; i < 4096; i += 256) {
    unsigned e7 = (w[i] >> 8) & 0x7F;
    if (e7 >= 0x3B && e7 <= 0x41) c++;
  }
  atomicAdd(&cnt, c);
  __syncthreads();
  if (threadIdx.x == 0) flag[0] = (cnt > 2048) ? 1 : 0;
}

__global__ __launch_bounds__(256) void conv_kernel(const void* src, float* dst,
                                                   long n, const int* flag) {
  long i = (long)blockIdx.x * 256 + threadIdx.x;
  int isb = flag[0];
  if (i < n) dst[i] = ld_elem(src, i, isb);
}

// ---------------------------------------------------------------------------
// trans: build Wbig (2048x4096 interleaved-4), Wms (1024x2048), WkT (512x1024),
// Wenc4 (1024x4096), bias4, zero xh/h, skeys.  grid (16384, 5)
// ---------------------------------------------------------------------------
__global__ __launch_bounds__(256) void trans_kernel(
    const void* W_ih, const void* W_hh, const void* W_mu, const void* W_sig,
    const void* W_k, const float* __restrict__ bihF, const float* __restrict__ bhhF,
    float* __restrict__ Wbig, float* __restrict__ Wms, float* __restrict__ WkT,
    float* __restrict__ Wenc4, float* __restrict__ bias4,
    float* __restrict__ xh, float* __restrict__ h, unsigned* __restrict__ skeys,
    const int* flag)
{
  long idx = (long)blockIdx.x * 256 + threadIdx.x;
  int y = blockIdx.y;
  int isb = flag[0];
  if (y == 0) {
    if (idx < 4194304) {
      int e = (int)(idx & 1023); int col = (int)(idx >> 10);
      int j = col >> 2, c = col & 3;
      float v = 0.f;
      if (c < 3) v = ld_elem(W_ih, (long)(c * 1024 + j) * 2048 + 1024 + e, isb);
      Wbig[(long)e * 4096 + col] = v;
    }
  } else if (y == 1) {
    if (idx < 4194304) {
      int e = (int)(idx & 1023); int col = (int)(idx >> 10);
      int j = col >> 2, c = col & 3;
      float v = 0.f;
      if (c == 0)      v = ld_elem(W_hh, (long)j * 1024 + e, isb);
      else if (c == 1) v = ld_elem(W_hh, (long)(1024 + j) * 1024 + e, isb);
      else if (c == 3) v = ld_elem(W_hh, (long)(2048 + j) * 1024 + e, isb);
      Wbig[(long)(1024 + e) * 4096 + col] = v;
    }
  } else if (y == 2) {
    if (idx < 2097152) {
      int k = (int)(idx >> 11), n = (int)(idx & 2047);
      float v = (n < 1024) ? ld_elem(W_mu, (long)k * 1024 + n, isb)
                           : ld_elem(W_sig, (long)k * 1024 + (n - 1024), isb);
      Wms[idx] = v;
    }
  } else if (y == 3) {
    if (idx < 524288) {
      int qk = (int)(idx >> 10), e = (int)(idx & 1023);
      WkT[idx] = ld_elem(W_k, (long)e * 512 + qk, isb);
    }
    if (idx < 4096) {
      int j = (int)(idx >> 2), c = (int)(idx & 3);
      float v;
      if (c == 0)      v = bihF[j] + bhhF[j];
      else if (c == 1) v = bihF[1024 + j] + bhhF[1024 + j];
      else if (c == 2) v = bihF[2048 + j];
      else             v = bhhF[2048 + j];
      bias4[idx] = v;
    }
    if (idx < 262144) xh[idx] = 0.f;
    if (idx < 131072) h[idx] = 0.f;
    if (idx < 128) {
      unsigned o0, o1;
      tf2x32(0u, 1234u, 0u, (unsigned)idx, o0, o1);
      skeys[2 * idx] = o0; skeys[2 * idx + 1] = o1;
    }
  } else {
    if (idx < 4194304) {
      int e = (int)(idx & 1023); int col = (int)(idx >> 10);
      int j = col >> 2, c = col & 3;
      float v = 0.f;
      if (c < 3) v = ld_elem(W_ih, (long)(c * 1024 + j) * 2048 + e, isb);
      Wenc4[(long)e * 4096 + col] = v;
    }
  }
}

// ---------------------------------------------------------------------------
// consts: bqk[h][e], qbc[h], bvo[e].  grid (32)
// ---------------------------------------------------------------------------
__global__ __launch_bounds__(256) void consts_kernel(
    const float* __restrict__ bqF, const float* __restrict__ bkF,
    const float* __restrict__ bvF, const float* __restrict__ boF,
    const float* __restrict__ WkT, const float* __restrict__ WoF,
    float* __restrict__ bqk, float* __restrict__ qbc, float* __restrict__ bvo)
{
  int idx = blockIdx.x * 256 + threadIdx.x;  // < 8192
  int hh = idx >> 10, e = idx & 1023;
  float s = 0.f;
  for (int a = 0; a < 64; ++a)
    s += bqF[hh * 64 + a] * WkT[(long)(hh * 64 + a) * 1024 + e];
  bqk[idx] = s;
  if (idx < 1024) {
    float v = boF[idx];
    for (int ha = 0; ha < 512; ++ha) v += bvF[ha] * WoF[(long)ha * 1024 + idx];
    bvo[idx] = v;
  }
  if (idx < 8) {
    float v = 0.f;
    for (int a = 0; a < 64; ++a) v += bqF[idx * 64 + a] * bkF[idx * 64 + a];
    qbc[idx] = v;
  }
}

// ---------------------------------------------------------------------------
// mm128: 128x128 tile, 8x8/thread, split-K partial store (baseline-verified)
// ---------------------------------------------------------------------------
__global__ __launch_bounds__(256) void mm128(
    const float* __restrict__ A, long lda, long zA, int nsumA, long psA,
    const float* __restrict__ Bm, long ldb, long zB,
    float* __restrict__ C, long ldc, long zC, long pstride,
    int Ktot, int S)
{
  int zz = blockIdx.z;
  int head = zz / S, sp = zz - head * S;
  int Kc = Ktot / S;
  long kb = (long)sp * Kc;
  A += (long)head * zA;
  Bm += (long)head * zB;
  C += (long)head * zC + (long)sp * pstride;
  long m0 = (long)blockIdx.y * 128;
  long n0 = (long)blockIdx.x * 128;
  __shared__ float As[16][132];
  __shared__ float Bs[16][132];
  int tid = threadIdx.x;
  int tx = tid & 15, ty = tid >> 4;
  int am = tid >> 2, ac = tid & 3;
  int bk = tid >> 5, bn = tid & 31;
  float acc[8][8];
  #pragma unroll
  for (int i = 0; i < 8; ++i)
    #pragma unroll
    for (int j = 0; j < 8; ++j) acc[i][j] = 0.f;

  for (int k0 = 0; k0 < Kc; k0 += 16) {
    const float* Ap0 = A + (m0 + am) * lda + kb + k0 + 4 * ac;
    const float* Ap1 = A + (m0 + am + 64) * lda + kb + k0 + 4 * ac;
    float4 a0 = *(const float4*)Ap0;
    float4 a1 = *(const float4*)Ap1;
    for (int s2 = 1; s2 < nsumA; ++s2) {
      float4 t0 = *(const float4*)(Ap0 + (long)s2 * psA);
      float4 t1 = *(const float4*)(Ap1 + (long)s2 * psA);
      a0.x += t0.x; a0.y += t0.y; a0.z += t0.z; a0.w += t0.w;
      a1.x += t1.x; a1.y += t1.y; a1.z += t1.z; a1.w += t1.w;
    }
    float4 b0 = *(const float4*)(Bm + (kb + k0 + bk) * ldb + n0 + 4 * bn);
    float4 b1 = *(const float4*)(Bm + (kb + k0 + bk + 8) * ldb + n0 + 4 * bn);
    __syncthreads();
    As[4 * ac + 0][am] = a0.x; As[4 * ac + 1][am] = a0.y;
    As[4 * ac + 2][am] = a0.z; As[4 * ac + 3][am] = a0.w;
    As[4 * ac + 0][am + 64] = a1.x; As[4 * ac + 1][am + 64] = a1.y;
    As[4 * ac + 2][am + 64] = a1.z; As[4 * ac + 3][am + 64] = a1.w;
    *(float4*)&Bs[bk][4 * bn] = b0;
    *(float4*)&Bs[bk + 8][4 * bn] = b1;
    __syncthreads();
    #pragma unroll
    for (int kk = 0; kk < 16; ++kk) {
      float4 av0 = *(const float4*)&As[kk][ty * 4];
      float4 av1 = *(const float4*)&As[kk][64 + ty * 4];
      float4 bv0 = *(const float4*)&Bs[kk][tx * 4];
      float4 bv1 = *(const float4*)&Bs[kk][64 + tx * 4];
      float amv[8] = {av0.x, av0.y, av0.z, av0.w, av1.x, av1.y, av1.z, av1.w};
      float bnv[8] = {bv0.x, bv0.y, bv0.z, bv0.w, bv1.x, bv1.y, bv1.z, bv1.w};
      #pragma unroll
      for (int i = 0; i < 8; ++i)
        #pragma unroll
        for (int j = 0; j < 8; ++j)
          acc[i][j] = fmaf(amv[i], bnv[j], acc[i][j]);
    }
  }

  #pragma unroll
  for (int i = 0; i < 8; ++i) {
    long r = m0 + (long)(i >> 2) * 64 + ty * 4 + (i & 3);
    float4 v0 = {acc[i][0], acc[i][1], acc[i][2], acc[i][3]};
    float4 v1 = {acc[i][4], acc[i][5], acc[i][6], acc[i][7]};
    *(float4*)(C + r * ldc + n0 + tx * 4) = v0;
    *(float4*)(C + r * ldc + n0 + 64 + tx * 4) = v1;
  }
}

// ---------------------------------------------------------------------------
// mm64s: 64x64 tile, 4x4/thread, split-K partial store (baseline, for V)
// ---------------------------------------------------------------------------
__global__ __launch_bounds__(256) void mm64s(
    const float* __restrict__ A, long lda, long zA,
    const float* __restrict__ Bm, long ldb, long zB,
    float* __restrict__ C, long ldc, long zC, long pstride,
    int Ktot, int S)
{
  int zz = blockIdx.z;
  int head = zz / S, sp = zz - head * S;
  int Kc = Ktot / S;
  long kb = (long)sp * Kc;
  A += (long)head * zA; Bm += (long)head * zB;
  C += (long)head * zC + (long)sp * pstride;
  long n0 = (long)blockIdx.x * 64;
  long m0 = (long)blockIdx.y * 64;
  __shared__ float As[16][68];
  __shared__ float Bs[16][68];
  int tid = threadIdx.x;
  int tx = tid & 15, ty = tid >> 4;
  int ar = tid >> 2, ac = tid & 3;
  int br = tid >> 4, bc = tid & 15;
  float acc[4][4];
  #pragma unroll
  for (int i = 0; i < 4; ++i)
    #pragma unroll
    for (int j = 0; j < 4; ++j) acc[i][j] = 0.f;

  for (int k0 = 0; k0 < Kc; k0 += 16) {
    float4 a4 = *(const float4*)(A + (m0 + ar) * lda + kb + k0 + 4 * ac);
    float4 b4 = *(const float4*)(Bm + (kb + k0 + br) * ldb + n0 + 4 * bc);
    __syncthreads();
    As[4 * ac + 0][ar] = a4.x; As[4 * ac + 1][ar] = a4.y;
    As[4 * ac + 2][ar] = a4.z; As[4 * ac + 3][ar] = a4.w;
    *(float4*)(&Bs[br][4 * bc]) = b4;
    __syncthreads();
    #pragma unroll
    for (int kk = 0; kk < 16; ++kk) {
      float4 av = *(const float4*)(&As[kk][4 * ty]);
      float4 bv = *(const float4*)(&Bs[kk][4 * tx]);
      float amv[4] = {av.x, av.y, av.z, av.w};
      float bnv[4] = {bv.x, bv.y, bv.z, bv.w};
      #pragma unroll
      for (int im = 0; im < 4; ++im)
        #pragma unroll
        for (int jn = 0; jn < 4; ++jn)
          acc[im][jn] = fmaf(amv[im], bnv[jn], acc[im][jn]);
    }
  }
  #pragma unroll
  for (int im = 0; im < 4; ++im) {
    long m = m0 + ty * 4 + im;
    float4 v = {acc[im][0], acc[im][1], acc[im][2], acc[im][3]};
    *(float4*)(C + m * ldc + n0 + tx * 4) = v;
  }
}

// ---------------------------------------------------------------------------
// gen_s device helper: rows [lo,hi) with step keys over nb virtual blocks
// ---------------------------------------------------------------------------
__device__ void gen_rows(int lo, int hi, int lbid, int nb, int step,
                         const float* __restrict__ mus,
                         const float* __restrict__ sigs,
                         float* __restrict__ s,
                         const unsigned* __restrict__ skeys, int tid) {
  int nvb = (hi - lo) * 128;
  if (nvb <= 0) return;
  unsigned sk0 = skeys[2 * step], sk1 = skeys[2 * step + 1];
  for (int vb = lbid; vb < nvb; vb += nb) {
    int t = lo + (vb >> 7);
    int b = vb & 127;
    int e = tid * 4;
    unsigned f = (unsigned)(b * (T_ * E_) + t * E_ + e);
    unsigned o0, o1;
    float nv[4];
    tf2x32(sk0, sk1, 0u, f + 0u, o0, o1); nv[0] = bits_to_normal(o0 ^ o1);
    tf2x32(sk0, sk1, 0u, f + 1u, o0, o1); nv[1] = bits_to_normal(o0 ^ o1);
    tf2x32(sk0, sk1, 0u, f + 2u, o0, o1); nv[2] = bits_to_normal(o0 ^ o1);
    tf2x32(sk0, sk1, 0u, f + 3u, o0, o1); nv[3] = bits_to_normal(o0 ^ o1);
    long i4 = (((long)b * T_ + t) * E_ + e) >> 2;
    float4 mu = ((const float4*)mus)[i4];
    float4 sg = ((const float4*)sigs)[i4];
    float4 out;
    out.x = fmaf(nv[0], sg.x, mu.x);
    out.y = fmaf(nv[1], sg.y, mu.y);
    out.z = fmaf(nv[2], sg.z, mu.z);
    out.w = fmaf(nv[3], sg.w, mu.w);
    ((float4*)s)[i4] = out;
  }
}

// ---------------------------------------------------------------------------
// GRU value helper: h_new quad for (batch b, H-cols j0..j0+3)
// ---------------------------------------------------------------------------
__device__ __forceinline__ float4 gru4(
    const float* __restrict__ gsumP, const float* __restrict__ gie4,
    const float* __restrict__ bias4, const float* __restrict__ hold,
    int b, int j0) {
  float4 ho = *(const float4*)&hold[(long)b * 1024 + j0];
  float hov[4] = {ho.x, ho.y, ho.z, ho.w};
  float ov[4];
  #pragma unroll
  for (int t = 0; t < 4; ++t) {
    int j = j0 + t;
    float4 v = ((const float4*)gie4)[(long)b * 1024 + j];
    float4 bb = ((const float4*)bias4)[j];
    v.x += bb.x; v.y += bb.y; v.z += bb.z; v.w += bb.w;
    #pragma unroll
    for (int s2 = 0; s2 < 8; ++s2) {
      float4 tq = ((const float4*)gsumP)[(long)s2 * 131072 + (long)b * 1024 + j];
      v.x += tq.x; v.y += tq.y; v.z += tq.z; v.w += tq.w;
    }
    float r = sigmoidf_(v.x);
    float z = sigmoidf_(v.y);
    float n = tanhf(v.z + r * v.w);
    ov[t] = (1.0f - z) * n + z * hov[t];
  }
  float4 out = {ov[0], ov[1], ov[2], ov[3]};
  return out;
}

// ---------------------------------------------------------------------------
// g2f: G2 GEMM (musigP = h_new @ Wms, split-8) with GRU fused into the
// A-operand (h_new computed on the fly from gsumP; bx==0 blocks persist
// h_new + xh h-half).  Blocks 128..255 generate old s rows [0, 2*step/3).
// grid (256)
// ---------------------------------------------------------------------------
__global__ __launch_bounds__(256) void g2f_kernel(
    const float* __restrict__ gsumP, const float* __restrict__ gie4,
    const float* __restrict__ bias4, const float* __restrict__ hold,
    float* __restrict__ hnew, float* __restrict__ xh,
    const float* __restrict__ Wms, float* __restrict__ musigP,
    const float* __restrict__ mus, const float* __restrict__ sigs,
    float* __restrict__ s, const unsigned* __restrict__ skeys, int step)
{
  int bid = blockIdx.x;
  int tid = threadIdx.x;
  if (bid >= 128) {
    int r1 = (2 * step) / 3;
    gen_rows(0, r1, bid - 128, 128, step, mus, sigs, s, skeys, tid);
    return;
  }
  int bx = bid & 15, sp = bid >> 4;
  long kb = (long)sp * 128;
  long n0 = (long)bx * 128;
  __shared__ float As[16][132];
  __shared__ float Bs[16][132];
  int tx = tid & 15, ty = tid >> 4;
  int am = tid >> 2, ac = tid & 3;
  int bk = tid >> 5, bn = tid & 31;
  float acc[8][8];
  #pragma unroll
  for (int i = 0; i < 8; ++i)
    #pragma unroll
    for (int j = 0; j < 8; ++j) acc[i][j] = 0.f;

  for (int k0 = 0; k0 < 128; k0 += 16) {
    int j0 = (int)kb + k0 + 4 * ac;
    float4 a0 = gru4(gsumP, gie4, bias4, hold, am, j0);
    float4 a1 = gru4(gsumP, gie4, bias4, hold, am + 64, j0);
    if (bx == 0) {  // persist h_new and xh h-half (exactly-once coverage)
      *(float4*)&hnew[(long)am * 1024 + j0] = a0;
      *(float4*)&hnew[(long)(am + 64) * 1024 + j0] = a1;
      *(float4*)&xh[(long)am * 2048 + 1024 + j0] = a0;
      *(float4*)&xh[(long)(am + 64) * 2048 + 1024 + j0] = a1;
    }
    float4 b0 = *(const float4*)(Wms + (kb + k0 + bk) * 2048 + n0 + 4 * bn);
    float4 b1 = *(const float4*)(Wms + (kb + k0 + bk + 8) * 2048 + n0 + 4 * bn);
    __syncthreads();
    As[4 * ac + 0][am] = a0.x; As[4 * ac + 1][am] = a0.y;
    As[4 * ac + 2][am] = a0.z; As[4 * ac + 3][am] = a0.w;
    As[4 * ac + 0][am + 64] = a1.x; As[4 * ac + 1][am + 64] = a1.y;
    As[4 * ac + 2][am + 64] = a1.z; As[4 * ac + 3][am + 64] = a1.w;
    *(float4*)&Bs[bk][4 * bn] = b0;
    *(float4*)&Bs[bk + 8][4 * bn] = b1;
    __syncthreads();
    #pragma unroll
    for (int kk = 0; kk < 16; ++kk) {
      float4 av0 = *(const float4*)&As[kk][ty * 4];
      float4 av1 = *(const float4*)&As[kk][64 + ty * 4];
      float4 bv0 = *(const float4*)&Bs[kk][tx * 4];
      float4 bv1 = *(const float4*)&Bs[kk][64 + tx * 4];
      float amv[8] = {av0.x, av0.y, av0.z, av0.w, av1.x, av1.y, av1.z, av1.w};
      float bnv[8] = {bv0.x, bv0.y, bv0.z, bv0.w, bv1.x, bv1.y, bv1.z, bv1.w};
      #pragma unroll
      for (int i = 0; i < 8; ++i)
        #pragma unroll
        for (int j = 0; j < 8; ++j)
          acc[i][j] = fmaf(amv[i], bnv[j], acc[i][j]);
    }
  }

  float* C = musigP + (long)sp * 262144;
  #pragma unroll
  for (int i = 0; i < 8; ++i) {
    long r = (long)(i >> 2) * 64 + ty * 4 + (i & 3);
    float4 v0 = {acc[i][0], acc[i][1], acc[i][2], acc[i][3]};
    float4 v1 = {acc[i][4], acc[i][5], acc[i][6], acc[i][7]};
    *(float4*)(C + r * 2048 + n0 + tx * 4) = v0;
    *(float4*)(C + r * 2048 + n0 + 64 + tx * 4) = v1;
  }
}

// ---------------------------------------------------------------------------
// qf: Q GEMM (qP = s_row_i @ Wq, 64x64 tiles, split-8) with musig epilogue +
// row-i sampling fused into the A-operand (bx==0 blocks persist mus/sigs/s).
// Blocks 128..255 generate old s rows [2*step/3, step).  grid (256)
// ---------------------------------------------------------------------------
__global__ __launch_bounds__(256) void qf_kernel(
    const float* __restrict__ musigP, const float* __restrict__ bmuF,
    const float* __restrict__ bsigF, float* __restrict__ mus,
    float* __restrict__ sigs, float* __restrict__ s,
    const float* __restrict__ Wq, float* __restrict__ qP,
    const unsigned* __restrict__ skeys, int step)
{
  int bid = blockIdx.x;
  int tid = threadIdx.x;
  if (bid >= 128) {
    int r1 = (2 * step) / 3;
    gen_rows(r1, step, bid - 128, 128, step, mus, sigs, s, skeys, tid);
    return;
  }
  int bx = bid & 7, by = (bid >> 3) & 1, sp = bid >> 4;
  long kb = (long)sp * 128;
  long n0 = (long)bx * 64;
  long m0 = (long)by * 64;
  __shared__ float As[16][68];
  __shared__ float Bs[16][68];
  int tx = tid & 15, ty = tid >> 4;
  int ar = tid >> 2, ac = tid & 3;
  int br = tid >> 4, bc = tid & 15;
  unsigned sk0 = skeys[2 * step], sk1 = skeys[2 * step + 1];
  float acc[4][4];
  #pragma unroll
  for (int i = 0; i < 4; ++i)
    #pragma unroll
    for (int j = 0; j < 4; ++j) acc[i][j] = 0.f;

  for (int k0 = 0; k0 < 128; k0 += 16) {
    int b = (int)m0 + ar;
    int e0 = (int)kb + k0 + 4 * ac;
    // musig from 8 partials
    float4 muq = ((const float4*)bmuF)[e0 >> 2];
    float4 xgq = ((const float4*)bsigF)[e0 >> 2];
    #pragma unroll
    for (int s2 = 0; s2 < 8; ++s2) {
      float4 tm = ((const float4*)musigP)[((long)s2 * 262144 + (long)b * 2048 + e0) >> 2];
      float4 tg = ((const float4*)musigP)[((long)s2 * 262144 + (long)b * 2048 + 1024 + e0) >> 2];
      muq.x += tm.x; muq.y += tm.y; muq.z += tm.z; muq.w += tm.w;
      xgq.x += tg.x; xgq.y += tg.y; xgq.z += tg.z; xgq.w += tg.w;
    }
    float4 sgq;
    sgq.x = fmaxf(xgq.x, 0.0f) + log1pf(expf(-fabsf(xgq.x)));
    sgq.y = fmaxf(xgq.y, 0.0f) + log1pf(expf(-fabsf(xgq.y)));
    sgq.z = fmaxf(xgq.z, 0.0f) + log1pf(expf(-fabsf(xgq.z)));
    sgq.w = fmaxf(xgq.w, 0.0f) + log1pf(expf(-fabsf(xgq.w)));
    // sample s row `step`
    unsigned f = (unsigned)(b * (T_ * E_) + step * E_ + e0);
    unsigned o0, o1;
    float4 a4;
    tf2x32(sk0, sk1, 0u, f + 0u, o0, o1); a4.x = fmaf(bits_to_normal(o0 ^ o1), sgq.x, muq.x);
    tf2x32(sk0, sk1, 0u, f + 1u, o0, o1); a4.y = fmaf(bits_to_normal(o0 ^ o1), sgq.y, muq.y);
    tf2x32(sk0, sk1, 0u, f + 2u, o0, o1); a4.z = fmaf(bits_to_normal(o0 ^ o1), sgq.z, muq.z);
    tf2x32(sk0, sk1, 0u, f + 3u, o0, o1); a4.w = fmaf(bits_to_normal(o0 ^ o1), sgq.w, muq.w);
    if (bx == 0) {  // persist mus/sigs/s row `step` (exactly-once coverage)
      long o = ((long)b * T_ + step) * E_ + e0;
      *(float4*)&mus[o] = muq;
      *(float4*)&sigs[o] = sgq;
      *(float4*)&s[o] = a4;
    }
    float4 b4 = *(const float4*)(Wq + (kb + k0 + br) * 512 + n0 + 4 * bc);
    __syncthreads();
    As[4 * ac + 0][ar] = a4.x; As[4 * ac + 1][ar] = a4.y;
    As[4 * ac + 2][ar] = a4.z; As[4 * ac + 3][ar] = a4.w;
    *(float4*)(&Bs[br][4 * bc]) = b4;
    __syncthreads();
    #pragma unroll
    for (int kk = 0; kk < 16; ++kk) {
      float4 av = *(const float4*)(&As[kk][4 * ty]);
      float4 bv = *(const float4*)(&Bs[kk][4 * tx]);
      float amv[4] = {av.x, av.y, av.z, av.w};
      float bnv[4] = {bv.x, bv.y, bv.z, bv.w};
      #pragma unroll
      for (int im = 0; im < 4; ++im)
        #pragma unroll
        for (int jn = 0; jn < 4; ++jn)
          acc[im][jn] = fmaf(amv[im], bnv[jn], acc[im][jn]);
    }
  }
  float* C = qP + (long)sp * 65536;
  #pragma unroll
  for (int im = 0; im < 4; ++im) {
    long m = m0 + ty * 4 + im;
    float4 v = {acc[im][0], acc[im][1], acc[im][2], acc[im][3]};
    *(float4*)(C + m * 512 + n0 + tx * 4) = v;
  }
}

// ---------------------------------------------------------------------------
// t_kernel (baseline-verified): t[b,h,e] = sum_a q[b,ha]*WkT[ha,e] + bqk;
// qb = q.bk + qbc.  q summed from 8 partials.  grid (4, 8, 16)
// ---------------------------------------------------------------------------
__global__ __launch_bounds__(256) void t_kernel(
    const float* __restrict__ qP, const float* __restrict__ WkT,
    const float* __restrict__ bkF, const float* __restrict__ bqk,
    const float* __restrict__ qbc, float* __restrict__ tmat,
    float* __restrict__ qb)
{
  int e = blockIdx.x * 256 + threadIdx.x;
  int hh = blockIdx.y;
  int b0 = blockIdx.z * 8;
  __shared__ float q_l[8][64];
  int tid = threadIdx.x;
  for (int idx2 = tid; idx2 < 512; idx2 += 256) {
    int bb = idx2 >> 6, a = idx2 & 63;
    float v = 0.f;
    #pragma unroll
    for (int s = 0; s < 8; ++s)
      v += qP[(long)s * 65536 + (long)(b0 + bb) * 512 + hh * 64 + a];
    q_l[bb][a] = v;
  }
  __syncthreads();
  float acc[8];
  #pragma unroll
  for (int bb = 0; bb < 8; ++bb) acc[bb] = 0.f;
  for (int a = 0; a < 64; ++a) {
    float wv = WkT[(long)(hh * 64 + a) * 1024 + e];
    #pragma unroll
    for (int bb = 0; bb < 8; ++bb) acc[bb] = fmaf(q_l[bb][a], wv, acc[bb]);
  }
  float bq_ = bqk[hh * 1024 + e];
  #pragma unroll
  for (int bb = 0; bb < 8; ++bb)
    tmat[((long)(b0 + bb) * NH_ + hh) * 1024 + e] = acc[bb] + bq_;
  if (blockIdx.x == 0 && tid < 8) {
    int bb = tid;
    float sm = qbc[hh];
    for (int a = 0; a < 64; ++a) sm += q_l[bb][a] * bkF[hh * 64 + a];
    qb[(b0 + bb) * NH_ + hh] = sm;
  }
}

// ---------------------------------------------------------------------------
// scores (baseline-verified): sc[b,h,j] = SCALE*(sum_e s[b,j,e]*t[b,h,e]+qb)
// grid (jt, 128)
// ---------------------------------------------------------------------------
__global__ __launch_bounds__(256) void scores_kernel(
    const float* __restrict__ s, const float* __restrict__ tmat,
    const float* __restrict__ qb, float* __restrict__ scg, int step)
{
  int b = blockIdx.y;
  int jbase = blockIdx.x * 32;
  __shared__ float s_ch[32][132];
  __shared__ float t_ch[8][132];
  int tid = threadIdx.x;
  int hh = tid >> 5, jj = tid & 31;
  int j = jbase + jj;
  float acc = 0.f;
  for (int e0 = 0; e0 < 1024; e0 += 128) {
    __syncthreads();
    #pragma unroll
    for (int q = 0; q < 4; ++q) {
      int f = tid + q * 256;
      int jr = f >> 5, e4 = f & 31;
      int jg = jbase + jr;
      if (jg <= step)
        *(float4*)&s_ch[jr][e4 * 4] =
            *(const float4*)&s[((long)b * T_ + jg) * E_ + e0 + e4 * 4];
    }
    {
      int e4 = tid & 31, h2 = tid >> 5;
      *(float4*)&t_ch[h2][e4 * 4] =
          *(const float4*)&tmat[((long)b * NH_ + h2) * E_ + e0 + e4 * 4];
    }
    __syncthreads();
    if (j <= step) {
      #pragma unroll
      for (int e4 = 0; e4 < 32; ++e4) {
        float4 sv = *(const float4*)&s_ch[jj][e4 * 4];
        float4 tv = *(const float4*)&t_ch[hh][e4 * 4];
        acc = fmaf(sv.x, tv.x, acc);
        acc = fmaf(sv.y, tv.y, acc);
        acc = fmaf(sv.z, tv.z, acc);
        acc = fmaf(sv.w, tv.w, acc);
      }
    }
  }
  if (j <= step)
    scg[((long)b * NH_ + hh) * T_ + j] = (acc + qb[b * NH_ + hh]) * SCALE_;
}

// ---------------------------------------------------------------------------
// ctx (baseline-verified): inline softmax + weighted sum of s.  grid (16,128)
// ---------------------------------------------------------------------------
__global__ __launch_bounds__(256) void ctx_kernel(
    const float* __restrict__ s, const float* __restrict__ scg,
    float* __restrict__ ctxE, int step)
{
  int b = blockIdx.y;
  int et = blockIdx.x;
  __shared__ float w_l[NH_][T_];
  __shared__ float s_l[32][68];
  int tid = threadIdx.x;
  {
    int hh = tid >> 5, l = tid & 31;
    const float* sc = scg + ((long)b * NH_ + hh) * T_;
    float m = -3.0e38f;
    for (int j = l; j <= step; j += 32) m = fmaxf(m, sc[j]);
    for (int off = 16; off; off >>= 1) m = fmaxf(m, __shfl_xor(m, off, 32));
    float d = 0.f;
    for (int j = l; j <= step; j += 32) {
      float pe = expf(sc[j] - m);
      w_l[hh][j] = pe;
      d += pe;
    }
    for (int off = 16; off; off >>= 1) d += __shfl_xor(d, off, 32);
    float inv = 1.0f / d;
    for (int j = l; j <= step; j += 32) w_l[hh][j] *= inv;
  }
  int e = tid & 63, hp = tid >> 6;  // hp 0..3, h in {hp, hp+4}
  float acc0 = 0.f, acc1 = 0.f;
  for (int jc = 0; jc <= step; jc += 32) {
    __syncthreads();
    #pragma unroll
    for (int q = 0; q < 8; ++q) {
      int f = tid + q * 256;
      int jr = f >> 6, ee = f & 63;
      int jg = jc + jr;
      if (jg <= step)
        s_l[jr][ee] = s[((long)b * T_ + jg) * E_ + et * 64 + ee];
    }
    __syncthreads();
    int jmax = min(31, step - jc);
    for (int jr = 0; jr <= jmax; ++jr) {
      float sv = s_l[jr][e];
      acc0 = fmaf(w_l[hp][jc + jr], sv, acc0);
      acc1 = fmaf(w_l[hp + 4][jc + jr], sv, acc1);
    }
  }
  ctxE[((long)b * NH_ + hp) * E_ + et * 64 + e] = acc0;
  ctxE[((long)b * NH_ + hp + 4) * E_ + et * 64 + e] = acc1;
}

// ---------------------------------------------------------------------------
// o_kernel: xh[:, :1024] = (sum4 ctxhP) @ Wo + bvo.  64x64 tiles, K=512,
// no split (A-load sums the 4 V partials).  grid (16, 2)
// ---------------------------------------------------------------------------
__global__ __launch_bounds__(256) void o_kernel(
    const float* __restrict__ ctxhP, const float* __restrict__ Wo,
    const float* __restrict__ bvo, float* __restrict__ xh)
{
  long n0 = (long)blockIdx.x * 64;
  long m0 = (long)blockIdx.y * 64;
  __shared__ float As[16][68];
  __shared__ float Bs[16][68];
  int tid = threadIdx.x;
  int tx = tid & 15, ty = tid >> 4;
  int ar = tid >> 2, ac = tid & 3;
  int br = tid >> 4, bc = tid & 15;
  float acc[4][4];
  #pragma unroll
  for (int i = 0; i < 4; ++i)
    #pragma unroll
    for (int j = 0; j < 4; ++j) acc[i][j] = 0.f;

  for (int k0 = 0; k0 < 512; k0 += 16) {
    const float* Ap = ctxhP + (m0 + ar) * 512 + k0 + 4 * ac;
    float4 a4 = *(const float4*)Ap;
    #pragma unroll
    for (int s2 = 1; s2 < 4; ++s2) {
      float4 t = *(const float4*)(Ap + (long)s2 * 65536);
      a4.x += t.x; a4.y += t.y; a4.z += t.z; a4.w += t.w;
    }
    float4 b4 = *(const float4*)(Wo + (k0 + br) * 1024 + n0 + 4 * bc);
    __syncthreads();
    As[4 * ac + 0][ar] = a4.x; As[4 * ac + 1][ar] = a4.y;
    As[4 * ac + 2][ar] = a4.z; As[4 * ac + 3][ar] = a4.w;
    *(float4*)(&Bs[br][4 * bc]) = b4;
    __syncthreads();
    #pragma unroll
    for (int kk = 0; kk < 16; ++kk) {
      float4 av = *(const float4*)(&As[kk][4 * ty]);
      float4 bv = *(const float4*)(&Bs[kk][4 * tx]);
      float amv[4] = {av.x, av.y, av.z, av.w};
      float bnv[4] = {bv.x, bv.y, bv.z, bv.w};
      #pragma unroll
      for (int im = 0; im < 4; ++im)
        #pragma unroll
        for (int jn = 0; jn < 4; ++jn)
          acc[im][jn] = fmaf(amv[im], bnv[jn], acc[im][jn]);
    }
  }
  float4 bq = ((const float4*)bvo)[(n0 + tx * 4) >> 2];
  #pragma unroll
  for (int im = 0; im < 4; ++im) {
    long m = m0 + ty * 4 + im;
    float4 v = {acc[im][0] + bq.x, acc[im][1] + bq.y,
                acc[im][2] + bq.z, acc[im][3] + bq.w};
    *(float4*)(xh + m * 2048 + n0 + tx * 4) = v;
  }
}

// ---------------------------------------------------------------------------
// Host side
// ---------------------------------------------------------------------------
extern "C" void kernel_launch(void* const* d_in, const int* in_sizes, int n_in,
                              void* d_out, int out_size, void* d_ws, size_t ws_size,
                              hipStream_t stream) {
  (void)in_sizes; (void)n_in; (void)out_size; (void)ws_size;
  const void* encs  = d_in[0];
  const void* W_ih  = d_in[1];
  const void* W_hh  = d_in[2];
  const void* b_ih  = d_in[3];
  const void* b_hh  = d_in[4];
  const void* W_mu  = d_in[5];
  const void* b_mu  = d_in[6];
  const void* W_sig = d_in[7];
  const void* b_sig = d_in[8];
  const void* W_q   = d_in[9];
  const void* b_q   = d_in[10];
  const void* W_k   = d_in[11];
  const void* b_k   = d_in[12];
  const void* W_v   = d_in[13];
  const void* b_v   = d_in[14];
  const void* W_o   = d_in[15];
  const void* b_o   = d_in[16];

  float* s = (float*)d_out;
  float* w = (float*)d_ws;

  int*   flag   = (int*)w;
  float* p      = w + 1024;
  float* WbigF  = p;  p += (size_t)2048 * 4096;   // 8.39M
  float* WmsF   = p;  p += (size_t)1024 * 2048;   // 2.10M
  float* WkTF   = p;  p += (size_t)512 * 1024;
  float* WqF    = p;  p += (size_t)1024 * 512;
  float* WvF    = p;  p += (size_t)1024 * 512;
  float* WoF    = p;  p += (size_t)512 * 1024;
  float* encsF  = p;  p += (size_t)B_ * E_;
  float* bihF   = p;  p += 4096;
  float* bhhF   = p;  p += 4096;
  float* bmuF   = p;  p += 1024;
  float* bsigF  = p;  p += 1024;
  float* bqF    = p;  p += 1024;
  float* bkF    = p;  p += 1024;
  float* bvF    = p;  p += 1024;
  float* boF    = p;  p += 1024;
  float* bias4  = p;  p += 4096;
  float* bqk    = p;  p += 8192;
  float* qbc    = p;  p += 1024;
  float* bvo    = p;  p += 1024;
  unsigned* skeys = (unsigned*)p; p += 1024;
  float* gie4   = p;  p += (size_t)B_ * 4096;     // 0.52M
  float* xh     = p;  p += (size_t)B_ * 2048;     // [ctx | h]
  float* hA     = p;  p += (size_t)B_ * 1024;     // h double buffer A (zeroed)
  float* hB     = p;  p += (size_t)B_ * 1024;     // h double buffer B
  float* gsumP  = p;  p += (size_t)8 * B_ * 4096; // 4.19M (aliased Wenc4 in prep)
  float* musigP = p;  p += (size_t)8 * B_ * 2048; // 2.10M
  float* qP     = p;  p += (size_t)8 * B_ * 512;  // 0.52M
  float* tmat   = p;  p += (size_t)B_ * NH_ * E_; // 1.05M
  float* qbv    = p;  p += 1024;
  float* scg    = p;  p += (size_t)B_ * NH_ * T_; // 0.13M
  float* ctxE   = p;  p += (size_t)B_ * NH_ * E_; // 1.05M
  float* ctxhP  = p;  p += (size_t)4 * B_ * 512;  // 0.26M
  float* mus    = p;  p += (size_t)B_ * T_ * E_;  // 16.8M
  float* sigs   = p;  p += (size_t)B_ * T_ * E_;  // 16.8M
  float* Wenc4  = gsumP;  // prep-only alias (consumed before first G1 write)

  // ---- prep ----
  sniff_kernel<<<1, 256, 0, stream>>>(encs, flag);
  auto conv = [&](const void* src, float* dst, long n) {
    conv_kernel<<<dim3((unsigned)((n + 255) / 256)), 256, 0, stream>>>(src, dst, n, flag);
  };
  conv(encs,  encsF, (long)B_ * E_);
  conv(b_ih,  bihF,  G_);
  conv(b_hh,  bhhF,  G_);
  conv(b_mu,  bmuF,  1024);
  conv(b_sig, bsigF, 1024);
  conv(b_q,   bqF,   512);
  conv(b_k,   bkF,   512);
  conv(b_v,   bvF,   512);
  conv(b_o,   boF,   1024);
  conv(W_q,   WqF,   (long)1024 * 512);
  conv(W_v,   WvF,   (long)1024 * 512);
  conv(W_o,   WoF,   (long)512 * 1024);

  trans_kernel<<<dim3(16384, 5), 256, 0, stream>>>(
      W_ih, W_hh, W_mu, W_sig, W_k, bihF, bhhF,
      WbigF, WmsF, WkTF, Wenc4, bias4, xh, hA, skeys, flag);
  consts_kernel<<<dim3(32), 256, 0, stream>>>(
      bqF, bkF, bvF, boF, WkTF, WoF, bqk, qbc, bvo);
  // gie4 = encs @ Wenc4  (reads the gsumP-aliased Wenc4 BEFORE the loop)
  mm128<<<dim3(32, 1, 1), 256, 0, stream>>>(
      encsF, 1024, 0, 1, 0, Wenc4, 4096, 0, gie4, 4096, 0, 0, 1024, 1);

  // ---- 128-step scan: 8 launches/step ----
  for (int i = 0; i < T_; ++i) {
    float* hold = (i & 1) ? hB : hA;
    float* hnew = (i & 1) ? hA : hB;
    // G1: gsumP = xh @ Wbig (interleaved r,z,inn,hn), split-8
    mm128<<<dim3(32, 1, 8), 256, 0, stream>>>(
        xh, 2048, 0, 1, 0, WbigF, 4096, 0, gsumP, 4096, 0, 524288, 2048, 8);
    // G2 + fused GRU (+gen_s rows [0, 2i/3))
    g2f_kernel<<<dim3(256), 256, 0, stream>>>(
        gsumP, gie4, bias4, hold, hnew, xh, WmsF, musigP, mus, sigs, s, skeys, i);
    // Q + fused musig/sample row i (+gen_s rows [2i/3, i))
    qf_kernel<<<dim3(256), 256, 0, stream>>>(
        musigP, bmuF, bsigF, mus, sigs, s, WqF, qP, skeys, i);
    t_kernel<<<dim3(4, 8, 16), 256, 0, stream>>>(
        qP, WkTF, bkF, bqk, qbc, tmat, qbv);
    scores_kernel<<<dim3((i + 32) / 32, B_), 256, 0, stream>>>(
        s, tmat, qbv, scg, i);
    ctx_kernel<<<dim3(16, B_), 256, 0, stream>>>(s, scg, ctxE, i);
    // V: ctxhP[s][b][h*64+a], per-head K=1024 split-4
    mm64s<<<dim3(1, 2, 32), 256, 0, stream>>>(
        ctxE, 8192, 1024, WvF, 512, 64, ctxhP, 512, 64, 65536, 1024, 4);
    // O fused with bvo + xh write (sums 4 V partials in A-load)
    o_kernel<<<dim3(16, 2), 256, 0, stream>>>(ctxhP, WoF, bvo, xh);
  }
  // d_out == s already holds step-127 sample (same fold_in(key,127) as eps_last)
}

// Round 7
// 33826.331 us; speedup vs baseline: 2.5818x; 1.1454x over previous
//
#include <hip/hip_runtime.h>

// Problem constants
#define B_   128
#define T_   128
#define E_   1024
#define H_   1024
#define A_   64
#define NH_  8
#define G_   3072
#define QK_  512
#define SCALE_ 0.125f

// ---------------------------------------------------------------------------
// JAX Threefry-2x32-20 (bit-exact) + XLA f32 erfinv path
// ---------------------------------------------------------------------------
__device__ __forceinline__ unsigned rotl32(unsigned x, int r) {
  return (x << r) | (x >> (32 - r));
}

__device__ __forceinline__ void tf2x32(unsigned k0, unsigned k1,
                                       unsigned x0, unsigned x1,
                                       unsigned& o0, unsigned& o1) {
  unsigned k2 = k0 ^ k1 ^ 0x1BD11BDAu;
  x0 += k0; x1 += k1;
  x0 += x1; x1 = rotl32(x1, 13); x1 ^= x0;
  x0 += x1; x1 = rotl32(x1, 15); x1 ^= x0;
  x0 += x1; x1 = rotl32(x1, 26); x1 ^= x0;
  x0 += x1; x1 = rotl32(x1,  6); x1 ^= x0;
  x0 += k1; x1 += k2 + 1u;
  x0 += x1; x1 = rotl32(x1, 17); x1 ^= x0;
  x0 += x1; x1 = rotl32(x1, 29); x1 ^= x0;
  x0 += x1; x1 = rotl32(x1, 16); x1 ^= x0;
  x0 += x1; x1 = rotl32(x1, 24); x1 ^= x0;
  x0 += k2; x1 += k0 + 2u;
  x0 += x1; x1 = rotl32(x1, 13); x1 ^= x0;
  x0 += x1; x1 = rotl32(x1, 15); x1 ^= x0;
  x0 += x1; x1 = rotl32(x1, 26); x1 ^= x0;
  x0 += x1; x1 = rotl32(x1,  6); x1 ^= x0;
  x0 += k0; x1 += k1 + 3u;
  x0 += x1; x1 = rotl32(x1, 17); x1 ^= x0;
  x0 += x1; x1 = rotl32(x1, 29); x1 ^= x0;
  x0 += x1; x1 = rotl32(x1, 16); x1 ^= x0;
  x0 += x1; x1 = rotl32(x1, 24); x1 ^= x0;
  x0 += k1; x1 += k2 + 4u;
  x0 += x1; x1 = rotl32(x1, 13); x1 ^= x0;
  x0 += x1; x1 = rotl32(x1, 15); x1 ^= x0;
  x0 += x1; x1 = rotl32(x1, 26); x1 ^= x0;
  x0 += x1; x1 = rotl32(x1,  6); x1 ^= x0;
  x0 += k2; x1 += k0 + 5u;
  o0 = x0; o1 = x1;
}

__device__ __forceinline__ float bits_to_normal(unsigned bits) {
  float uf = __uint_as_float((bits >> 9) | 0x3F800000u) - 1.0f;
  const float LO = -0.99999994f;
  float u = fmaxf(LO, uf * 2.0f + LO);
  float w = -log1pf(-u * u);
  float p;
  if (w < 5.0f) {
    w -= 2.5f;
    p = 2.81022636e-08f;
    p = fmaf(p, w, 3.43273939e-07f);
    p = fmaf(p, w, -3.5233877e-06f);
    p = fmaf(p, w, -4.39150654e-06f);
    p = fmaf(p, w, 0.00021858087f);
    p = fmaf(p, w, -0.00125372503f);
    p = fmaf(p, w, -0.00417768164f);
    p = fmaf(p, w, 0.246640727f);
    p = fmaf(p, w, 1.50140941f);
  } else {
    w = sqrtf(w) - 3.0f;
    p = -0.000200214257f;
    p = fmaf(p, w, 0.000100950558f);
    p = fmaf(p, w, 0.00134934322f);
    p = fmaf(p, w, -0.00367342844f);
    p = fmaf(p, w, 0.00573950773f);
    p = fmaf(p, w, -0.0076224613f);
    p = fmaf(p, w, 0.00943887047f);
    p = fmaf(p, w, 1.00167406f);
    p = fmaf(p, w, 2.83297682f);
  }
  return 1.41421356f * p * u;
}

__device__ __forceinline__ float sigmoidf_(float x) {
  return 1.0f / (1.0f + expf(-x));
}

__device__ __forceinline__ float ld_elem(const void* p, long i, int isb) {
  if (isb) {
    unsigned short u = ((const unsigned short*)p)[i];
    return __uint_as_float(((unsigned)u) << 16);
  }
  return ((const float*)p)[i];
}

// ---------------------------------------------------------------------------
// dtype sniffer + converter (verified)
// ---------------------------------------------------------------------------
__global__ __launch_bounds__(256) void sniff_kernel(const void* encs, int* flag) {
  __shared__ int cnt;
  if (threadIdx.x == 0) cnt = 0;
  __syncthreads();
  const unsigned* w = (const unsigned*)encs;
  int c = 0;
  for (int i = threadIdx.x; i < 4096; i += 256) {
    unsigned e7 = (w[i] >> 8) & 0x7F;
    if (e7 >= 0x3B && e7 <= 0x41) c++;
  }
  atomicAdd(&cnt, c);
  __syncthreads();
  if (threadIdx.x == 0) flag[0] = (cnt > 2048) ? 1 : 0;
}

__global__ __launch_bounds__(256) void conv_kernel(const void* src, float* dst,
                                                   long n, const int* flag) {
  long i = (long)blockIdx.x * 256 + threadIdx.x;
  int isb = flag[0];
  if (i < n) dst[i] = ld_elem(src, i, isb);
}

// ---------------------------------------------------------------------------
// trans: build Wbig (2048x4096 interleaved-4), Wms (1024x2048), WkT (512x1024),
// Wenc4 (1024x4096), bias4, zero xh/h, skeys.  grid (16384, 5)
// ---------------------------------------------------------------------------
__global__ __launch_bounds__(256) void trans_kernel(
    const void* W_ih, const void* W_hh, const void* W_mu, const void* W_sig,
    const void* W_k, const float* __restrict__ bihF, const float* __restrict__ bhhF,
    float* __restrict__ Wbig, float* __restrict__ Wms, float* __restrict__ WkT,
    float* __restrict__ Wenc4, float* __restrict__ bias4,
    float* __restrict__ xh, float* __restrict__ h, unsigned* __restrict__ skeys,
    const int* flag)
{
  long idx = (long)blockIdx.x * 256 + threadIdx.x;
  int y = blockIdx.y;
  int isb = flag[0];
  if (y == 0) {
    if (idx < 4194304) {
      int e = (int)(idx & 1023); int col = (int)(idx >> 10);
      int j = col >> 2, c = col & 3;
      float v = 0.f;
      if (c < 3) v = ld_elem(W_ih, (long)(c * 1024 + j) * 2048 + 1024 + e, isb);
      Wbig[(long)e * 4096 + col] = v;
    }
  } else if (y == 1) {
    if (idx < 4194304) {
      int e = (int)(idx & 1023); int col = (int)(idx >> 10);
      int j = col >> 2, c = col & 3;
      float v = 0.f;
      if (c == 0)      v = ld_elem(W_hh, (long)j * 1024 + e, isb);
      else if (c == 1) v = ld_elem(W_hh, (long)(1024 + j) * 1024 + e, isb);
      else if (c == 3) v = ld_elem(W_hh, (long)(2048 + j) * 1024 + e, isb);
      Wbig[(long)(1024 + e) * 4096 + col] = v;
    }
  } else if (y == 2) {
    if (idx < 2097152) {
      int k = (int)(idx >> 11), n = (int)(idx & 2047);
      float v = (n < 1024) ? ld_elem(W_mu, (long)k * 1024 + n, isb)
                           : ld_elem(W_sig, (long)k * 1024 + (n - 1024), isb);
      Wms[idx] = v;
    }
  } else if (y == 3) {
    if (idx < 524288) {
      int qk = (int)(idx >> 10), e = (int)(idx & 1023);
      WkT[idx] = ld_elem(W_k, (long)e * 512 + qk, isb);
    }
    if (idx < 4096) {
      int j = (int)(idx >> 2), c = (int)(idx & 3);
      float v;
      if (c == 0)      v = bihF[j] + bhhF[j];
      else if (c == 1) v = bihF[1024 + j] + bhhF[1024 + j];
      else if (c == 2) v = bihF[2048 + j];
      else             v = bhhF[2048 + j];
      bias4[idx] = v;
    }
    if (idx < 262144) xh[idx] = 0.f;
    if (idx < 131072) h[idx] = 0.f;
    if (idx < 128) {
      unsigned o0, o1;
      tf2x32(0u, 1234u, 0u, (unsigned)idx, o0, o1);
      skeys[2 * idx] = o0; skeys[2 * idx + 1] = o1;
    }
  } else {
    if (idx < 4194304) {
      int e = (int)(idx & 1023); int col = (int)(idx >> 10);
      int j = col >> 2, c = col & 3;
      float v = 0.f;
      if (c < 3) v = ld_elem(W_ih, (long)(c * 1024 + j) * 2048 + e, isb);
      Wenc4[(long)e * 4096 + col] = v;
    }
  }
}

// ---------------------------------------------------------------------------
// consts: bqk[h][e], qbc[h], bvo[e].  grid (32)
// ---------------------------------------------------------------------------
__global__ __launch_bounds__(256) void consts_kernel(
    const float* __restrict__ bqF, const float* __restrict__ bkF,
    const float* __restrict__ bvF, const float* __restrict__ boF,
    const float* __restrict__ WkT, const float* __restrict__ WoF,
    float* __restrict__ bqk, float* __restrict__ qbc, float* __restrict__ bvo)
{
  int idx = blockIdx.x * 256 + threadIdx.x;  // < 8192
  int hh = idx >> 10, e = idx & 1023;
  float s = 0.f;
  for (int a = 0; a < 64; ++a)
    s += bqF[hh * 64 + a] * WkT[(long)(hh * 64 + a) * 1024 + e];
  bqk[idx] = s;
  if (idx < 1024) {
    float v = boF[idx];
    for (int ha = 0; ha < 512; ++ha) v += bvF[ha] * WoF[(long)ha * 1024 + idx];
    bvo[idx] = v;
  }
  if (idx < 8) {
    float v = 0.f;
    for (int a = 0; a < 64; ++a) v += bqF[idx * 64 + a] * bkF[idx * 64 + a];
    qbc[idx] = v;
  }
}

// ---------------------------------------------------------------------------
// mm128 device fn: 128x128 tile, 8x8/thread, split-K partial store
// (verified numerically in R2/R5 megakernel runs; plain stores)
// ---------------------------------------------------------------------------
__device__ void mm128_dev(float* smem,
    const float* A, long lda, long zA, int nsumA, long psA,
    const float* Bm, long ldb, long zB,
    float* C, long ldc, long zC, long pstride,
    int Ktot, int S, int bx, int by, int zz, int tid)
{
  int head = zz / S, sp = zz - head * S;
  int Kc = Ktot / S;
  long kb = (long)sp * Kc;
  A += (long)head * zA;
  Bm += (long)head * zB;
  C += (long)head * zC + (long)sp * pstride;
  long m0 = (long)by * 128;
  long n0 = (long)bx * 128;
  float* As = smem;            // [16][132]
  float* Bs = smem + 2112;     // [16][132]
  int tx = tid & 15, ty = tid >> 4;
  int am = tid >> 2, ac = tid & 3;
  int bk = tid >> 5, bn = tid & 31;
  float acc[8][8];
  #pragma unroll
  for (int i = 0; i < 8; ++i)
    #pragma unroll
    for (int j = 0; j < 8; ++j) acc[i][j] = 0.f;

  for (int k0 = 0; k0 < Kc; k0 += 16) {
    const float* Ap0 = A + (m0 + am) * lda + kb + k0 + 4 * ac;
    const float* Ap1 = A + (m0 + am + 64) * lda + kb + k0 + 4 * ac;
    float4 a0 = *(const float4*)Ap0;
    float4 a1 = *(const float4*)Ap1;
    for (int s2 = 1; s2 < nsumA; ++s2) {
      float4 t0 = *(const float4*)(Ap0 + (long)s2 * psA);
      float4 t1 = *(const float4*)(Ap1 + (long)s2 * psA);
      a0.x += t0.x; a0.y += t0.y; a0.z += t0.z; a0.w += t0.w;
      a1.x += t1.x; a1.y += t1.y; a1.z += t1.z; a1.w += t1.w;
    }
    float4 b0 = *(const float4*)(Bm + (kb + k0 + bk) * ldb + n0 + 4 * bn);
    float4 b1 = *(const float4*)(Bm + (kb + k0 + bk + 8) * ldb + n0 + 4 * bn);
    __syncthreads();
    As[(4 * ac + 0) * 132 + am] = a0.x; As[(4 * ac + 1) * 132 + am] = a0.y;
    As[(4 * ac + 2) * 132 + am] = a0.z; As[(4 * ac + 3) * 132 + am] = a0.w;
    As[(4 * ac + 0) * 132 + am + 64] = a1.x; As[(4 * ac + 1) * 132 + am + 64] = a1.y;
    As[(4 * ac + 2) * 132 + am + 64] = a1.z; As[(4 * ac + 3) * 132 + am + 64] = a1.w;
    *(float4*)&Bs[bk * 132 + 4 * bn] = b0;
    *(float4*)&Bs[(bk + 8) * 132 + 4 * bn] = b1;
    __syncthreads();
    #pragma unroll
    for (int kk = 0; kk < 16; ++kk) {
      float4 av0 = *(const float4*)&As[kk * 132 + ty * 4];
      float4 av1 = *(const float4*)&As[kk * 132 + 64 + ty * 4];
      float4 bv0 = *(const float4*)&Bs[kk * 132 + tx * 4];
      float4 bv1 = *(const float4*)&Bs[kk * 132 + 64 + tx * 4];
      float amv[8] = {av0.x, av0.y, av0.z, av0.w, av1.x, av1.y, av1.z, av1.w};
      float bnv[8] = {bv0.x, bv0.y, bv0.z, bv0.w, bv1.x, bv1.y, bv1.z, bv1.w};
      #pragma unroll
      for (int i = 0; i < 8; ++i)
        #pragma unroll
        for (int j = 0; j < 8; ++j)
          acc[i][j] = fmaf(amv[i], bnv[j], acc[i][j]);
    }
  }

  #pragma unroll
  for (int i = 0; i < 8; ++i) {
    long r = m0 + (long)(i >> 2) * 64 + ty * 4 + (i & 3);
    float4 v0 = {acc[i][0], acc[i][1], acc[i][2], acc[i][3]};
    float4 v1 = {acc[i][4], acc[i][5], acc[i][6], acc[i][7]};
    *(float4*)(C + r * ldc + n0 + tx * 4) = v0;
    *(float4*)(C + r * ldc + n0 + 64 + tx * 4) = v1;
  }
}

// Standalone mm128 wrapper (prep gie4)
__global__ __launch_bounds__(256) void mm128(
    const float* A, long lda, long zA, int nsumA, long psA,
    const float* Bm, long ldb, long zB,
    float* C, long ldc, long zC, long pstride, int Ktot, int S)
{
  __shared__ __align__(16) float smem[4224];
  mm128_dev(smem, A, lda, zA, nsumA, psA, Bm, ldb, zB, C, ldc, zC, pstride,
            Ktot, S, blockIdx.x, blockIdx.y, blockIdx.z, threadIdx.x);
}

// ---------------------------------------------------------------------------
// mm64s: 64x64 tile, 4x4/thread, split-K partial store (baseline-verified;
// used for Q wide (8,2,8) and V (1,2,32))
// ---------------------------------------------------------------------------
__global__ __launch_bounds__(256) void mm64s(
    const float* __restrict__ A, long lda, long zA,
    const float* __restrict__ Bm, long ldb, long zB,
    float* __restrict__ C, long ldc, long zC, long pstride,
    int Ktot, int S)
{
  int zz = blockIdx.z;
  int head = zz / S, sp = zz - head * S;
  int Kc = Ktot / S;
  long kb = (long)sp * Kc;
  A += (long)head * zA; Bm += (long)head * zB;
  C += (long)head * zC + (long)sp * pstride;
  long n0 = (long)blockIdx.x * 64;
  long m0 = (long)blockIdx.y * 64;
  __shared__ float As[16][68];
  __shared__ float Bs[16][68];
  int tid = threadIdx.x;
  int tx = tid & 15, ty = tid >> 4;
  int ar = tid >> 2, ac = tid & 3;
  int br = tid >> 4, bc = tid & 15;
  float acc[4][4];
  #pragma unroll
  for (int i = 0; i < 4; ++i)
    #pragma unroll
    for (int j = 0; j < 4; ++j) acc[i][j] = 0.f;

  for (int k0 = 0; k0 < Kc; k0 += 16) {
    float4 a4 = *(const float4*)(A + (m0 + ar) * lda + kb + k0 + 4 * ac);
    float4 b4 = *(const float4*)(Bm + (kb + k0 + br) * ldb + n0 + 4 * bc);
    __syncthreads();
    As[4 * ac + 0][ar] = a4.x; As[4 * ac + 1][ar] = a4.y;
    As[4 * ac + 2][ar] = a4.z; As[4 * ac + 3][ar] = a4.w;
    *(float4*)(&Bs[br][4 * bc]) = b4;
    __syncthreads();
    #pragma unroll
    for (int kk = 0; kk < 16; ++kk) {
      float4 av = *(const float4*)(&As[kk][4 * ty]);
      float4 bv = *(const float4*)(&Bs[kk][4 * tx]);
      float amv[4] = {av.x, av.y, av.z, av.w};
      float bnv[4] = {bv.x, bv.y, bv.z, bv.w};
      #pragma unroll
      for (int im = 0; im < 4; ++im)
        #pragma unroll
        for (int jn = 0; jn < 4; ++jn)
          acc[im][jn] = fmaf(amv[im], bnv[jn], acc[im][jn]);
    }
  }
  #pragma unroll
  for (int im = 0; im < 4; ++im) {
    long m = m0 + ty * 4 + im;
    float4 v = {acc[im][0], acc[im][1], acc[im][2], acc[im][3]};
    *(float4*)(C + m * ldc + n0 + tx * 4) = v;
  }
}

// ---------------------------------------------------------------------------
// gen_s device helper (R6-verified): rows [lo,hi), step keys, nb virt blocks
// ---------------------------------------------------------------------------
__device__ void gen_rows(int lo, int hi, int lbid, int nb, int step,
                         const float* __restrict__ mus,
                         const float* __restrict__ sigs,
                         float* __restrict__ s,
                         const unsigned* __restrict__ skeys, int tid) {
  int nvb = (hi - lo) * 128;
  if (nvb <= 0) return;
  unsigned sk0 = skeys[2 * step], sk1 = skeys[2 * step + 1];
  for (int vb = lbid; vb < nvb; vb += nb) {
    int t = lo + (vb >> 7);
    int b = vb & 127;
    int e = tid * 4;
    unsigned f = (unsigned)(b * (T_ * E_) + t * E_ + e);
    unsigned o0, o1;
    float nv[4];
    tf2x32(sk0, sk1, 0u, f + 0u, o0, o1); nv[0] = bits_to_normal(o0 ^ o1);
    tf2x32(sk0, sk1, 0u, f + 1u, o0, o1); nv[1] = bits_to_normal(o0 ^ o1);
    tf2x32(sk0, sk1, 0u, f + 2u, o0, o1); nv[2] = bits_to_normal(o0 ^ o1);
    tf2x32(sk0, sk1, 0u, f + 3u, o0, o1); nv[3] = bits_to_normal(o0 ^ o1);
    long i4 = (((long)b * T_ + t) * E_ + e) >> 2;
    float4 mu = ((const float4*)mus)[i4];
    float4 sg = ((const float4*)sigs)[i4];
    float4 out;
    out.x = fmaf(nv[0], sg.x, mu.x);
    out.y = fmaf(nv[1], sg.y, mu.y);
    out.z = fmaf(nv[2], sg.z, mu.z);
    out.w = fmaf(nv[3], sg.w, mu.w);
    ((float4*)s)[i4] = out;
  }
}

// ---------------------------------------------------------------------------
// g1gen: G1 GEMM (blocks 0..255, verbatim mm128 math) + gen_s rows [0,2i/3)
// on blocks 256..511.  grid (512)
// ---------------------------------------------------------------------------
__global__ __launch_bounds__(256) void g1gen_kernel(
    const float* __restrict__ xh, const float* __restrict__ Wbig,
    float* __restrict__ gsumP,
    const float* __restrict__ mus, const float* __restrict__ sigs,
    float* __restrict__ s, const unsigned* __restrict__ skeys, int step)
{
  __shared__ __align__(16) float smem[4224];
  int bid = blockIdx.x, tid = threadIdx.x;
  if (bid < 256) {
    mm128_dev(smem, xh, 2048, 0, 1, 0, Wbig, 4096, 0,
              gsumP, 4096, 0, 524288, 2048, 8, bid & 31, 0, bid >> 5, tid);
  } else {
    int r1 = (2 * step) / 3;
    gen_rows(0, r1, bid - 256, 256, step, mus, sigs, s, skeys, tid);
  }
}

// ---------------------------------------------------------------------------
// GRU epilogue (baseline-verified): sum 8 partials + gie4 + bias4 -> h, xh
// ---------------------------------------------------------------------------
__global__ __launch_bounds__(256) void gru_epi(
    const float* __restrict__ gsumP, const float* __restrict__ gie4,
    const float* __restrict__ bias4, float* __restrict__ h,
    float* __restrict__ xh)
{
  int idx = blockIdx.x * 256 + threadIdx.x;  // < B*H
  int b = idx >> 10, j = idx & 1023;
  float4 v = ((const float4*)gie4)[(long)b * 1024 + j];
  float4 bb = ((const float4*)bias4)[j];
  v.x += bb.x; v.y += bb.y; v.z += bb.z; v.w += bb.w;
  #pragma unroll
  for (int s = 0; s < 8; ++s) {
    float4 t = ((const float4*)gsumP)[(long)s * 131072 + (long)b * 1024 + j];
    v.x += t.x; v.y += t.y; v.z += t.z; v.w += t.w;
  }
  float r = sigmoidf_(v.x);
  float z = sigmoidf_(v.y);
  float n = tanhf(v.z + r * v.w);
  float ho = h[idx];
  float hn = (1.0f - z) * n + z * ho;
  h[idx] = hn;
  xh[(long)b * 2048 + 1024 + j] = hn;
}

// ---------------------------------------------------------------------------
// g2gen: G2 GEMM (blocks 0..127) + gen_s rows [2i/3,i) on blocks 128..255.
// grid (256)
// ---------------------------------------------------------------------------
__global__ __launch_bounds__(256) void g2gen_kernel(
    const float* __restrict__ hbuf, const float* __restrict__ Wms,
    float* __restrict__ musigP,
    const float* __restrict__ mus, const float* __restrict__ sigs,
    float* __restrict__ s, const unsigned* __restrict__ skeys, int step)
{
  __shared__ __align__(16) float smem[4224];
  int bid = blockIdx.x, tid = threadIdx.x;
  if (bid < 128) {
    mm128_dev(smem, hbuf, 1024, 0, 1, 0, Wms, 2048, 0,
              musigP, 2048, 0, 262144, 1024, 8, bid & 15, 0, bid >> 4, tid);
  } else {
    int r1 = (2 * step) / 3;
    gen_rows(r1, step, bid - 128, 128, step, mus, sigs, s, skeys, tid);
  }
}

// ---------------------------------------------------------------------------
// msgen: musig epilogue (sum 8 partials + bias, softplus) + sample s row i.
// Coalesced, 1 element/thread.  grid (512)
// ---------------------------------------------------------------------------
__global__ __launch_bounds__(256) void msgen_kernel(
    const float* __restrict__ musigP, const float* __restrict__ bmuF,
    const float* __restrict__ bsigF, float* __restrict__ mus,
    float* __restrict__ sigs, float* __restrict__ s,
    const unsigned* __restrict__ skeys, int step)
{
  int el = blockIdx.x * 256 + threadIdx.x;  // < 131072
  int b = el >> 10, e = el & 1023;
  float mu = bmuF[e], xg = bsigF[e];
  #pragma unroll
  for (int s2 = 0; s2 < 8; ++s2) {
    mu += musigP[(long)s2 * 262144 + (long)b * 2048 + e];
    xg += musigP[(long)s2 * 262144 + (long)b * 2048 + 1024 + e];
  }
  float sig = fmaxf(xg, 0.0f) + log1pf(expf(-fabsf(xg)));
  long o = ((long)b * T_ + step) * E_ + e;
  mus[o] = mu;
  sigs[o] = sig;
  unsigned sk0 = skeys[2 * step], sk1 = skeys[2 * step + 1];
  unsigned f = (unsigned)(b * (T_ * E_) + step * E_ + e);
  unsigned o0, o1;
  tf2x32(sk0, sk1, 0u, f, o0, o1);
  s[o] = fmaf(bits_to_normal(o0 ^ o1), sig, mu);
}

// ---------------------------------------------------------------------------
// t_kernel (baseline-verified)
// ---------------------------------------------------------------------------
__global__ __launch_bounds__(256) void t_kernel(
    const float* __restrict__ qP, const float* __restrict__ WkT,
    const float* __restrict__ bkF, const float* __restrict__ bqk,
    const float* __restrict__ qbc, float* __restrict__ tmat,
    float* __restrict__ qb)
{
  int e = blockIdx.x * 256 + threadIdx.x;
  int hh = blockIdx.y;
  int b0 = blockIdx.z * 8;
  __shared__ float q_l[8][64];
  int tid = threadIdx.x;
  for (int idx2 = tid; idx2 < 512; idx2 += 256) {
    int bb = idx2 >> 6, a = idx2 & 63;
    float v = 0.f;
    #pragma unroll
    for (int s = 0; s < 8; ++s)
      v += qP[(long)s * 65536 + (long)(b0 + bb) * 512 + hh * 64 + a];
    q_l[bb][a] = v;
  }
  __syncthreads();
  float acc[8];
  #pragma unroll
  for (int bb = 0; bb < 8; ++bb) acc[bb] = 0.f;
  for (int a = 0; a < 64; ++a) {
    float wv = WkT[(long)(hh * 64 + a) * 1024 + e];
    #pragma unroll
    for (int bb = 0; bb < 8; ++bb) acc[bb] = fmaf(q_l[bb][a], wv, acc[bb]);
  }
  float bq_ = bqk[hh * 1024 + e];
  #pragma unroll
  for (int bb = 0; bb < 8; ++bb)
    tmat[((long)(b0 + bb) * NH_ + hh) * 1024 + e] = acc[bb] + bq_;
  if (blockIdx.x == 0 && tid < 8) {
    int bb = tid;
    float sm = qbc[hh];
    for (int a = 0; a < 64; ++a) sm += q_l[bb][a] * bkF[hh * 64 + a];
    qb[(b0 + bb) * NH_ + hh] = sm;
  }
}

// ---------------------------------------------------------------------------
// scores (baseline-verified)
// ---------------------------------------------------------------------------
__global__ __launch_bounds__(256) void scores_kernel(
    const float* __restrict__ s, const float* __restrict__ tmat,
    const float* __restrict__ qb, float* __restrict__ scg, int step)
{
  int b = blockIdx.y;
  int jbase = blockIdx.x * 32;
  __shared__ float s_ch[32][132];
  __shared__ float t_ch[8][132];
  int tid = threadIdx.x;
  int hh = tid >> 5, jj = tid & 31;
  int j = jbase + jj;
  float acc = 0.f;
  for (int e0 = 0; e0 < 1024; e0 += 128) {
    __syncthreads();
    #pragma unroll
    for (int q = 0; q < 4; ++q) {
      int f = tid + q * 256;
      int jr = f >> 5, e4 = f & 31;
      int jg = jbase + jr;
      if (jg <= step)
        *(float4*)&s_ch[jr][e4 * 4] =
            *(const float4*)&s[((long)b * T_ + jg) * E_ + e0 + e4 * 4];
    }
    {
      int e4 = tid & 31, h2 = tid >> 5;
      *(float4*)&t_ch[h2][e4 * 4] =
          *(const float4*)&tmat[((long)b * NH_ + h2) * E_ + e0 + e4 * 4];
    }
    __syncthreads();
    if (j <= step) {
      #pragma unroll
      for (int e4 = 0; e4 < 32; ++e4) {
        float4 sv = *(const float4*)&s_ch[jj][e4 * 4];
        float4 tv = *(const float4*)&t_ch[hh][e4 * 4];
        acc = fmaf(sv.x, tv.x, acc);
        acc = fmaf(sv.y, tv.y, acc);
        acc = fmaf(sv.z, tv.z, acc);
        acc = fmaf(sv.w, tv.w, acc);
      }
    }
  }
  if (j <= step)
    scg[((long)b * NH_ + hh) * T_ + j] = (acc + qb[b * NH_ + hh]) * SCALE_;
}

// ---------------------------------------------------------------------------
// ctx (baseline-verified): inline softmax + weighted sum of s.  grid (16,128)
// ---------------------------------------------------------------------------
__global__ __launch_bounds__(256) void ctx_kernel(
    const float* __restrict__ s, const float* __restrict__ scg,
    float* __restrict__ ctxE, int step)
{
  int b = blockIdx.y;
  int et = blockIdx.x;
  __shared__ float w_l[NH_][T_];
  __shared__ float s_l[32][68];
  int tid = threadIdx.x;
  {
    int hh = tid >> 5, l = tid & 31;
    const float* sc = scg + ((long)b * NH_ + hh) * T_;
    float m = -3.0e38f;
    for (int j = l; j <= step; j += 32) m = fmaxf(m, sc[j]);
    for (int off = 16; off; off >>= 1) m = fmaxf(m, __shfl_xor(m, off, 32));
    float d = 0.f;
    for (int j = l; j <= step; j += 32) {
      float pe = expf(sc[j] - m);
      w_l[hh][j] = pe;
      d += pe;
    }
    for (int off = 16; off; off >>= 1) d += __shfl_xor(d, off, 32);
    float inv = 1.0f / d;
    for (int j = l; j <= step; j += 32) w_l[hh][j] *= inv;
  }
  int e = tid & 63, hp = tid >> 6;  // hp 0..3, h in {hp, hp+4}
  float acc0 = 0.f, acc1 = 0.f;
  for (int jc = 0; jc <= step; jc += 32) {
    __syncthreads();
    #pragma unroll
    for (int q = 0; q < 8; ++q) {
      int f = tid + q * 256;
      int jr = f >> 6, ee = f & 63;
      int jg = jc + jr;
      if (jg <= step)
        s_l[jr][ee] = s[((long)b * T_ + jg) * E_ + et * 64 + ee];
    }
    __syncthreads();
    int jmax = min(31, step - jc);
    for (int jr = 0; jr <= jmax; ++jr) {
      float sv = s_l[jr][e];
      acc0 = fmaf(w_l[hp][jc + jr], sv, acc0);
      acc1 = fmaf(w_l[hp + 4][jc + jr], sv, acc1);
    }
  }
  ctxE[((long)b * NH_ + hp) * E_ + et * 64 + e] = acc0;
  ctxE[((long)b * NH_ + hp + 4) * E_ + et * 64 + e] = acc1;
}

// ---------------------------------------------------------------------------
// o_kernel (R6-verified): xh[:, :1024] = (sum4 ctxhP) @ Wo + bvo.
// 64x64 tiles, K=512 unsplit.  grid (16, 2)
// ---------------------------------------------------------------------------
__global__ __launch_bounds__(256) void o_kernel(
    const float* __restrict__ ctxhP, const float* __restrict__ Wo,
    const float* __restrict__ bvo, float* __restrict__ xh)
{
  long n0 = (long)blockIdx.x * 64;
  long m0 = (long)blockIdx.y * 64;
  __shared__ float As[16][68];
  __shared__ float Bs[16][68];
  int tid = threadIdx.x;
  int tx = tid & 15, ty = tid >> 4;
  int ar = tid >> 2, ac = tid & 3;
  int br = tid >> 4, bc = tid & 15;
  float acc[4][4];
  #pragma unroll
  for (int i = 0; i < 4; ++i)
    #pragma unroll
    for (int j = 0; j < 4; ++j) acc[i][j] = 0.f;

  for (int k0 = 0; k0 < 512; k0 += 16) {
    const float* Ap = ctxhP + (m0 + ar) * 512 + k0 + 4 * ac;
    float4 a4 = *(const float4*)Ap;
    #pragma unroll
    for (int s2 = 1; s2 < 4; ++s2) {
      float4 t = *(const float4*)(Ap + (long)s2 * 65536);
      a4.x += t.x; a4.y += t.y; a4.z += t.z; a4.w += t.w;
    }
    float4 b4 = *(const float4*)(Wo + (k0 + br) * 1024 + n0 + 4 * bc);
    __syncthreads();
    As[4 * ac + 0][ar] = a4.x; As[4 * ac + 1][ar] = a4.y;
    As[4 * ac + 2][ar] = a4.z; As[4 * ac + 3][ar] = a4.w;
    *(float4*)(&Bs[br][4 * bc]) = b4;
    __syncthreads();
    #pragma unroll
    for (int kk = 0; kk < 16; ++kk) {
      float4 av = *(const float4*)(&As[kk][4 * ty]);
      float4 bv = *(const float4*)(&Bs[kk][4 * tx]);
      float amv[4] = {av.x, av.y, av.z, av.w};
      float bnv[4] = {bv.x, bv.y, bv.z, bv.w};
      #pragma unroll
      for (int im = 0; im < 4; ++im)
        #pragma unroll
        for (int jn = 0; jn < 4; ++jn)
          acc[im][jn] = fmaf(amv[im], bnv[jn], acc[im][jn]);
    }
  }
  float4 bq = ((const float4*)bvo)[(n0 + tx * 4) >> 2];
  #pragma unroll
  for (int im = 0; im < 4; ++im) {
    long m = m0 + ty * 4 + im;
    float4 v = {acc[im][0] + bq.x, acc[im][1] + bq.y,
                acc[im][2] + bq.z, acc[im][3] + bq.w};
    *(float4*)(xh + m * 2048 + n0 + tx * 4) = v;
  }
}

// ---------------------------------------------------------------------------
// Host side
// ---------------------------------------------------------------------------
extern "C" void kernel_launch(void* const* d_in, const int* in_sizes, int n_in,
                              void* d_out, int out_size, void* d_ws, size_t ws_size,
                              hipStream_t stream) {
  (void)in_sizes; (void)n_in; (void)out_size; (void)ws_size;
  const void* encs  = d_in[0];
  const void* W_ih  = d_in[1];
  const void* W_hh  = d_in[2];
  const void* b_ih  = d_in[3];
  const void* b_hh  = d_in[4];
  const void* W_mu  = d_in[5];
  const void* b_mu  = d_in[6];
  const void* W_sig = d_in[7];
  const void* b_sig = d_in[8];
  const void* W_q   = d_in[9];
  const void* b_q   = d_in[10];
  const void* W_k   = d_in[11];
  const void* b_k   = d_in[12];
  const void* W_v   = d_in[13];
  const void* b_v   = d_in[14];
  const void* W_o   = d_in[15];
  const void* b_o   = d_in[16];

  float* s = (float*)d_out;
  float* w = (float*)d_ws;

  int*   flag   = (int*)w;
  float* p      = w + 1024;
  float* WbigF  = p;  p += (size_t)2048 * 4096;   // 8.39M
  float* WmsF   = p;  p += (size_t)1024 * 2048;   // 2.10M
  float* WkTF   = p;  p += (size_t)512 * 1024;
  float* WqF    = p;  p += (size_t)1024 * 512;
  float* WvF    = p;  p += (size_t)1024 * 512;
  float* WoF    = p;  p += (size_t)512 * 1024;
  float* encsF  = p;  p += (size_t)B_ * E_;
  float* bihF   = p;  p += 4096;
  float* bhhF   = p;  p += 4096;
  float* bmuF   = p;  p += 1024;
  float* bsigF  = p;  p += 1024;
  float* bqF    = p;  p += 1024;
  float* bkF    = p;  p += 1024;
  float* bvF    = p;  p += 1024;
  float* boF    = p;  p += 1024;
  float* bias4  = p;  p += 4096;
  float* bqk    = p;  p += 8192;
  float* qbc    = p;  p += 1024;
  float* bvo    = p;  p += 1024;
  unsigned* skeys = (unsigned*)p; p += 1024;
  float* gie4   = p;  p += (size_t)B_ * 4096;     // 0.52M
  float* xh     = p;  p += (size_t)B_ * 2048;     // [ctx | h]
  float* hbuf   = p;  p += (size_t)B_ * 1024;
  float* gsumP  = p;  p += (size_t)8 * B_ * 4096; // 4.19M (aliased Wenc4 in prep)
  float* musigP = p;  p += (size_t)8 * B_ * 2048; // 2.10M
  float* qP     = p;  p += (size_t)8 * B_ * 512;  // 0.52M
  float* tmat   = p;  p += (size_t)B_ * NH_ * E_; // 1.05M
  float* qbv    = p;  p += 1024;
  float* scg    = p;  p += (size_t)B_ * NH_ * T_; // 0.13M
  float* ctxE   = p;  p += (size_t)B_ * NH_ * E_; // 1.05M
  float* ctxhP  = p;  p += (size_t)4 * B_ * 512;  // 0.26M
  float* mus    = p;  p += (size_t)B_ * T_ * E_;  // 16.8M
  float* sigs   = p;  p += (size_t)B_ * T_ * E_;  // 16.8M
  float* Wenc4  = gsumP;  // prep-only alias (consumed before first G1 write)

  // ---- prep ----
  sniff_kernel<<<1, 256, 0, stream>>>(encs, flag);
  auto conv = [&](const void* src, float* dst, long n) {
    conv_kernel<<<dim3((unsigned)((n + 255) / 256)), 256, 0, stream>>>(src, dst, n, flag);
  };
  conv(encs,  encsF, (long)B_ * E_);
  conv(b_ih,  bihF,  G_);
  conv(b_hh,  bhhF,  G_);
  conv(b_mu,  bmuF,  1024);
  conv(b_sig, bsigF, 1024);
  conv(b_q,   bqF,   512);
  conv(b_k,   bkF,   512);
  conv(b_v,   bvF,   512);
  conv(b_o,   boF,   1024);
  conv(W_q,   WqF,   (long)1024 * 512);
  conv(W_v,   WvF,   (long)1024 * 512);
  conv(W_o,   WoF,   (long)512 * 1024);

  trans_kernel<<<dim3(16384, 5), 256, 0, stream>>>(
      W_ih, W_hh, W_mu, W_sig, W_k, bihF, bhhF,
      WbigF, WmsF, WkTF, Wenc4, bias4, xh, hbuf, skeys, flag);
  consts_kernel<<<dim3(32), 256, 0, stream>>>(
      bqF, bkF, bvF, boF, WkTF, WoF, bqk, qbc, bvo);
  // gie4 = encs @ Wenc4  (reads the gsumP-aliased Wenc4 BEFORE the loop)
  mm128<<<dim3(32, 1, 1), 256, 0, stream>>>(
      encsF, 1024, 0, 1, 0, Wenc4, 4096, 0, gie4, 4096, 0, 0, 1024, 1);

  // ---- 128-step scan: 10 launches/step ----
  for (int i = 0; i < T_; ++i) {
    // G1 (256 blocks) + gen_s rows [0,2i/3) (256 blocks)
    g1gen_kernel<<<dim3(512), 256, 0, stream>>>(
        xh, WbigF, gsumP, mus, sigs, s, skeys, i);
    gru_epi<<<dim3(512), 256, 0, stream>>>(gsumP, gie4, bias4, hbuf, xh);
    // G2 (128 blocks) + gen_s rows [2i/3,i) (128 blocks)
    g2gen_kernel<<<dim3(256), 256, 0, stream>>>(
        hbuf, WmsF, musigP, mus, sigs, s, skeys, i);
    // musig epilogue + sample s row i
    msgen_kernel<<<dim3(512), 256, 0, stream>>>(
        musigP, bmuF, bsigF, mus, sigs, s, skeys, i);
    // Q: qP = s_i @ Wq, 64x64 tiles split-8 (128 blocks)
    mm64s<<<dim3(8, 2, 8), 256, 0, stream>>>(
        s + (long)i * E_, (long)T_ * E_, 0, WqF, 512, 0,
        qP, 512, 0, 65536, 1024, 8);
    t_kernel<<<dim3(4, 8, 16), 256, 0, stream>>>(
        qP, WkTF, bkF, bqk, qbc, tmat, qbv);
    scores_kernel<<<dim3((i + 32) / 32, B_), 256, 0, stream>>>(
        s, tmat, qbv, scg, i);
    ctx_kernel<<<dim3(16, B_), 256, 0, stream>>>(s, scg, ctxE, i);
    // V: ctxhP[s][b][h*64+a], per-head K=1024 split-4
    mm64s<<<dim3(1, 2, 32), 256, 0, stream>>>(
        ctxE, 8192, 1024, WvF, 512, 64, ctxhP, 512, 64, 65536, 1024, 4);
    // O fused with bvo + xh write (sums 4 V partials in A-load)
    o_kernel<<<dim3(16, 2), 256, 0, stream>>>(ctxhP, WoF, bvo, xh);
  }
  // d_out == s already holds step-127 sample (same fold_in(key,127) as eps_last)
}